// Round 1
// baseline (227.202 us; speedup 1.0000x reference)
//
#include <hip/hip_runtime.h>
#include <hip/hip_fp16.h>

#define D 32          // MOTIF_DIM
#define H 64          // HIDDEN

typedef __attribute__((ext_vector_type(8))) _Float16 f16x8;
typedef __attribute__((ext_vector_type(4))) float f32x4;

union AB { uint4 u; f16x8 v; __half2 h2[4]; };

// DPP 16-lane row reduction (rows of 16 = our q-groups). All VALU, no DS.
template <int CTRL>
__device__ __forceinline__ float dppadd(float x) {
  int s = __builtin_amdgcn_update_dpp(0, __float_as_int(x), CTRL, 0xF, 0xF, true);
  return x + __int_as_float(s);
}
__device__ __forceinline__ float row16_sum(float x) {
  x = dppadd<0xB1>(x);    // quad_perm [1,0,3,2]  : lane ^ 1
  x = dppadd<0x4E>(x);    // quad_perm [2,3,0,1]  : lane ^ 2
  x = dppadd<0x141>(x);   // row_half_mirror
  x = dppadd<0x140>(x);   // row_mirror
  return x;
}

// ---------------------------------------------------------------------------
// Fused prep: blocks [0, nPack) convert x fp32 -> fp16 rows (RNE);
// remaining blocks build the W1 B-fragment table in fp16 (16 frags x 64
// lanes x 8 = 16 KB). Frag f = t*4+s: lane l elem j = W1[s*32+(l>>4)*8+j][t*16+(l&15)].
// ---------------------------------------------------------------------------
__global__ __launch_bounds__(256) void prep(
    const float* __restrict__ x, const float* __restrict__ W1,
    unsigned short* __restrict__ xh, unsigned short* __restrict__ btab,
    int n4, int nPack) {
  int b = blockIdx.x;
  if (b < nPack) {
    int i = b * 256 + threadIdx.x;
    if (i < n4) {
      float4 v = ((const float4*)x)[i];
      ushort4 o;
      o.x = __half_as_ushort(__float2half(v.x));
      o.y = __half_as_ushort(__float2half(v.y));
      o.z = __half_as_ushort(__float2half(v.z));
      o.w = __half_as_ushort(__float2half(v.w));
      ((ushort4*)xh)[i] = o;
    }
  } else {
    int id = (b - nPack) * 256 + threadIdx.x;      // 0..8191
    if (id < 16 * 64 * 8) {
      int j = id & 7;
      int l = (id >> 3) & 63;
      int f = id >> 9;
      int s = f & 3, t = f >> 2;
      int k = s * 32 + (l >> 4) * 8 + j;
      int n = t * 16 + (l & 15);
      btab[id] = __half_as_ushort(__float2half(W1[k * H + n]));
    }
  }
}

// ---------------------------------------------------------------------------
// Compute a PAIR of 16-edge tiles with B-fragment reuse: each of the 16
// B-frags is ds_read ONCE per pair and feeds both tiles' MFMAs. A-frags:
// mu,mv gathered fp16; c,p via packed-fp16 VALU. Bias as MFMA C-input;
// fused layer-2, DPP row-reduce, sigmoid, guarded writes.
// ebase = first edge of tile0 (tile1 = ebase+16), pre-clamped so that
// ebase+31 < nE always holds for reads; store guards keep writes exact.
// ---------------------------------------------------------------------------
__device__ __forceinline__ void compute_pair(
    uint4 mu0U, uint4 mv0U, uint4 mu1U, uint4 mv1U,
    const _Float16* __restrict__ bl,
    const float* __restrict__ b1v, const float* __restrict__ w2v, float bias2,
    int ebase, int q, int m, int nE, float* __restrict__ out) {
  AB mu0, mv0, mu1, mv1, ac0, ap0, ac1, ap1;
  mu0.u = mu0U; mv0.u = mv0U; mu1.u = mu1U; mv1.u = mv1U;
#pragma unroll
  for (int k = 0; k < 4; ++k) {
    ac0.h2[k] = __habs2(__hsub2(mu0.h2[k], mv0.h2[k]));
    ap0.h2[k] = __hmul2(mu0.h2[k], mv0.h2[k]);
    ac1.h2[k] = __habs2(__hsub2(mu1.h2[k], mv1.h2[k]));
    ap1.h2[k] = __hmul2(mu1.h2[k], mv1.h2[k]);
  }

  float part0[4], part1[4];
#pragma unroll
  for (int t = 0; t < 4; ++t) {
    float bv = b1v[t];
    f32x4 acc0 = (f32x4){bv, bv, bv, bv};
    f32x4 acc1 = (f32x4){bv, bv, bv, bv};
    // one ds_read per fragment, two MFMAs (both tiles)
    f16x8 B0 = *(const f16x8*)(bl + (t * 4 + 0) * 512);
    acc0 = __builtin_amdgcn_mfma_f32_16x16x32_f16(mu0.v, B0, acc0, 0, 0, 0);
    acc1 = __builtin_amdgcn_mfma_f32_16x16x32_f16(mu1.v, B0, acc1, 0, 0, 0);
    f16x8 B1 = *(const f16x8*)(bl + (t * 4 + 1) * 512);
    acc0 = __builtin_amdgcn_mfma_f32_16x16x32_f16(mv0.v, B1, acc0, 0, 0, 0);
    acc1 = __builtin_amdgcn_mfma_f32_16x16x32_f16(mv1.v, B1, acc1, 0, 0, 0);
    f16x8 B2 = *(const f16x8*)(bl + (t * 4 + 2) * 512);
    acc0 = __builtin_amdgcn_mfma_f32_16x16x32_f16(ac0.v, B2, acc0, 0, 0, 0);
    acc1 = __builtin_amdgcn_mfma_f32_16x16x32_f16(ac1.v, B2, acc1, 0, 0, 0);
    f16x8 B3 = *(const f16x8*)(bl + (t * 4 + 3) * 512);
    acc0 = __builtin_amdgcn_mfma_f32_16x16x32_f16(ap0.v, B3, acc0, 0, 0, 0);
    acc1 = __builtin_amdgcn_mfma_f32_16x16x32_f16(ap1.v, B3, acc1, 0, 0, 0);
#pragma unroll
    for (int r = 0; r < 4; ++r) {
      float h0 = fmaxf(acc0[r], 0.f);
      float h1 = fmaxf(acc1[r], 0.f);
      part0[r] = (t == 0) ? h0 * w2v[0] : fmaf(h0, w2v[t], part0[r]);
      part1[r] = (t == 0) ? h1 * w2v[0] : fmaf(h1, w2v[t], part1[r]);
    }
  }

#pragma unroll
  for (int r = 0; r < 4; ++r) {
    part0[r] = row16_sum(part0[r]);
    part1[r] = row16_sum(part1[r]);
  }

  if (m < 4) {
    float z0 = (m == 0 ? part0[0] : m == 1 ? part0[1] : m == 2 ? part0[2] : part0[3]) + bias2;
    float z1 = (m == 0 ? part1[0] : m == 1 ? part1[1] : m == 2 ? part1[2] : part1[3]) + bias2;
    int ew0 = ebase + q * 4 + m;
    int ew1 = ebase + 16 + q * 4 + m;
    if (ew0 < nE) out[ew0] = 1.f / (1.f + __expf(-z0));
    if (ew1 < nE) out[ew1] = 1.f / (1.f + __expf(-z1));
  }
}

// ---------------------------------------------------------------------------
// Main: pairs of consecutive 16-edge tiles per wave, grid-stride, hand-
// unrolled x2 (no register-rotation movs). Indices loaded DIRECTLY per lane
// (4 saddr dword loads/pair, each one L1 line) -- no ds_bpermute chain.
// Pair base uniformly clamped to nE-32 (tail pair recomputes a few edges,
// idempotent). idx prefetched 2 pairs ahead, gathers 1 pair ahead.
// B table staged into LDS with coalesced uint4 copies; anti-LICM opacifier
// on the INTEGER offset only (pointer opacification kills LDS provenance).
// __launch_bounds__(256,8): pin 64 VGPR -> 8 waves/SIMD (prev build used
// exactly 64 with MORE live state, so no spill expected).
// ---------------------------------------------------------------------------
__global__ __launch_bounds__(256, 8) void edge_mfma(
    const unsigned short* __restrict__ xh, const unsigned short* __restrict__ btab,
    const int* __restrict__ ei,
    const float* __restrict__ b1, const float* __restrict__ W2,
    const float* __restrict__ b2, float* __restrict__ out,
    int nE, int nPairs) {
  __shared__ _Float16 lds_b[16 * 64 * 8];   // 16 KB

  // stage B table: 1024 uint4, 256 threads x 4 (coalesced)
  {
    const uint4* src = (const uint4*)btab;
    uint4* dst = (uint4*)lds_b;
#pragma unroll
    for (int i = 0; i < 4; ++i)
      dst[threadIdx.x + i * 256] = src[threadIdx.x + i * 256];
  }
  __syncthreads();

  int lane = threadIdx.x & 63;
  int wid  = (blockIdx.x * 256 + threadIdx.x) >> 6;
  int nW   = (gridDim.x * 256) >> 6;
  int m = lane & 15;        // edge-in-tile (A rows) / hidden-in-tile (C cols)
  int q = lane >> 4;        // quad
  if (wid >= nPairs) return;

  float b1v[4], w2v[4];
#pragma unroll
  for (int t = 0; t < 4; ++t) {
    b1v[t] = b1[t * 16 + m];
    w2v[t] = W2[t * 16 + m];
  }
  float bias2 = b2[0];

  const uint4* xb = (const uint4*)xh;    // node row = 4 uint4; lane reads row*4+q
  const int* eis = ei;                   // src ids
  const int* eid = ei + nE;              // dst ids
  int pLim = nPairs - 1;
  int eCap = nE - 32;                    // launcher guarantees nE >= 32

  // ---- prologue: gathers for pair wid, idx for pair wid+nW ----
  int p = wid;
  int pbC = p * 32; pbC = pbC < eCap ? pbC : eCap;
  {
    int o0 = pbC + m;
    int ia = eis[o0], ib = eis[o0 + 16], ic = eid[o0], id_ = eid[o0 + 16];
    // fallthrough into gathers below via a/b names
    uint4 t0 = xb[ia * 4 + q], t1 = xb[ib * 4 + q];
    uint4 t2 = xb[ic * 4 + q], t3 = xb[id_ * 4 + q];
    // assign to the rotating register set A
    // (SSA: these are the pair-p gathers)
    // store into named regs:
    // amu0,amu1 = src rows tile0/1 ; amv0,amv1 = dst rows tile0/1
    #define AMU0 t0
    // -- use direct variables instead of macros below --
    // (kept simple: re-declare outside this scope)
    asm volatile("" ::);  // no-op
    // move out of scope via globals below
    // NOTE: restructured right after this block.
    (void)t0; (void)t1; (void)t2; (void)t3;
  }
  // Restructured prologue (kept linear for clean SSA):
  uint4 amu0, amu1, amv0, amv1;
  {
    int o0 = pbC + m;
    int ia = eis[o0], ib = eis[o0 + 16], ic = eid[o0], id_ = eid[o0 + 16];
    amu0 = xb[ia * 4 + q]; amu1 = xb[ib * 4 + q];
    amv0 = xb[ic * 4 + q]; amv1 = xb[id_ * 4 + q];
  }
  int ja, jb, jc, jd;
  int pbN;
  {
    int p1 = p + nW; p1 = p1 < pLim ? p1 : pLim;
    pbN = p1 * 32; pbN = pbN < eCap ? pbN : eCap;
    int o1 = pbN + m;
    ja = eis[o1]; jb = eis[o1 + 16]; jc = eid[o1]; jd = eid[o1 + 16];
  }

  uint4 bmu0, bmu1, bmv0, bmv1;
  while (true) {
    // ---- step A: compute A-set, prefetch gathers into B-set ----
    bmu0 = xb[ja * 4 + q]; bmu1 = xb[jb * 4 + q];
    bmv0 = xb[jc * 4 + q]; bmv1 = xb[jd * 4 + q];
    int pb2;
    {
      int p2 = p + 2 * nW; p2 = p2 < pLim ? p2 : pLim;
      pb2 = p2 * 32; pb2 = pb2 < eCap ? pb2 : eCap;
      int o2 = pb2 + m;
      ja = eis[o2]; jb = eis[o2 + 16]; jc = eid[o2]; jd = eid[o2 + 16];
    }
    {
      int bofs = lane * 8;
      asm volatile("" : "+v"(bofs));
      compute_pair(amu0, amv0, amu1, amv1, lds_b + bofs, b1v, w2v, bias2,
                   pbC, q, m, nE, out);
    }
    p += nW; if (p > pLim) return;
    pbC = pbN; pbN = pb2;

    // ---- step B: compute B-set, prefetch gathers into A-set ----
    amu0 = xb[ja * 4 + q]; amu1 = xb[jb * 4 + q];
    amv0 = xb[jc * 4 + q]; amv1 = xb[jd * 4 + q];
    {
      int p2 = p + 2 * nW; p2 = p2 < pLim ? p2 : pLim;
      pb2 = p2 * 32; pb2 = pb2 < eCap ? pb2 : eCap;
      int o2 = pb2 + m;
      ja = eis[o2]; jb = eis[o2 + 16]; jc = eid[o2]; jd = eid[o2 + 16];
    }
    {
      int bofs = lane * 8;
      asm volatile("" : "+v"(bofs));
      compute_pair(bmu0, bmv0, bmu1, bmv1, lds_b + bofs, b1v, w2v, bias2,
                   pbC, q, m, nE, out);
    }
    p += nW; if (p > pLim) return;
    pbC = pbN; pbN = pb2;
  }
}

// ---------------------------------------------------------------------------
// Fallback (ws too small or nE < 32): all-fp32 per edge, no workspace needed.
// ---------------------------------------------------------------------------
__global__ __launch_bounds__(256) void edge_full(
    const float* __restrict__ x, const int* __restrict__ ei,
    const float* __restrict__ W1, const float* __restrict__ b1,
    const float* __restrict__ W2, const float* __restrict__ b2,
    float* __restrict__ out, int nE) {
  int e = blockIdx.x * 256 + threadIdx.x;
  if (e >= nE) return;
  int s = ei[e];
  int d = ei[e + nE];
  const float4* mu4 = (const float4*)(x + (size_t)s * D);
  const float4* mv4 = (const float4*)(x + (size_t)d * D);
  float mu[D], mv[D], c[D], p[D];
#pragma unroll
  for (int qq = 0; qq < D / 4; ++qq) {
    float4 a = mu4[qq];
    float4 b = mv4[qq];
    mu[4*qq+0] = a.x; mv[4*qq+0] = b.x; c[4*qq+0] = fabsf(a.x-b.x); p[4*qq+0] = a.x*b.x;
    mu[4*qq+1] = a.y; mv[4*qq+1] = b.y; c[4*qq+1] = fabsf(a.y-b.y); p[4*qq+1] = a.y*b.y;
    mu[4*qq+2] = a.z; mv[4*qq+2] = b.z; c[4*qq+2] = fabsf(a.z-b.z); p[4*qq+2] = a.z*b.z;
    mu[4*qq+3] = a.w; mv[4*qq+3] = b.w; c[4*qq+3] = fabsf(a.w-b.w); p[4*qq+3] = a.w*b.w;
  }
  float z = b2[0];
  for (int j = 0; j < H; ++j) {
    float a = b1[j];
#pragma unroll
    for (int k = 0; k < D; ++k) {
      a = fmaf(mu[k], W1[k * H + j], a);
      a = fmaf(mv[k], W1[(D + k) * H + j], a);
      a = fmaf(c[k],  W1[(2 * D + k) * H + j], a);
      a = fmaf(p[k],  W1[(3 * D + k) * H + j], a);
    }
    a = fmaxf(a, 0.f);
    z = fmaf(a, W2[j], z);
  }
  float g = 1.f / (1.f + __expf(-z));
  out[e] = fminf(fmaxf(g, 0.f), 1.f);
}

extern "C" void kernel_launch(void* const* d_in, const int* in_sizes, int n_in,
                              void* d_out, int out_size, void* d_ws, size_t ws_size,
                              hipStream_t stream) {
  const float* x  = (const float*)d_in[0];
  const int*   ei = (const int*)d_in[1];
  const float* W1 = (const float*)d_in[2];
  const float* b1 = (const float*)d_in[3];
  const float* W2 = (const float*)d_in[4];
  const float* b2 = (const float*)d_in[5];
  float* out = (float*)d_out;

  int nN = in_sizes[0] / D;      // 100000
  int nE = in_sizes[1] / 2;      // 1600000

  size_t xh_shorts = (size_t)nN * D;                      // 6.4 MB
  size_t need = (xh_shorts + 16 * 64 * 8) * sizeof(unsigned short);
  if (ws_size >= need && nE >= 32) {
    unsigned short* xh   = (unsigned short*)d_ws;
    unsigned short* btab = xh + xh_shorts;
    int n4 = nN * D / 4;
    int nPack = (n4 + 255) / 256;
    int nBt = (16 * 64 * 8 + 255) / 256;
    prep<<<nPack + nBt, 256, 0, stream>>>(x, W1, xh, btab, n4, nPack);
    int nTiles = (nE + 15) / 16;
    int nPairs = (nTiles + 1) / 2;
    // 4 waves/block x 4 pairs/wave: exact balance for nPairs=50000 (3125 blocks)
    int blocks = (nPairs + 15) / 16;
    if (blocks < 1) blocks = 1;
    edge_mfma<<<blocks, 256, 0, stream>>>(xh, btab, ei, b1, W2, b2, out, nE, nPairs);
  } else {
    edge_full<<<(nE + 255) / 256, 256, 0, stream>>>(x, ei, W1, b1, W2, b2, out, nE);
  }
}

// Round 4
// 141.236 us; speedup vs baseline: 1.6087x; 1.6087x over previous
//
#include <hip/hip_runtime.h>
#include <hip/hip_fp16.h>

#define D 32          // MOTIF_DIM
#define H 64          // HIDDEN

typedef __attribute__((ext_vector_type(8))) _Float16 f16x8;
typedef __attribute__((ext_vector_type(4))) float f32x4;

union AB { uint4 u; f16x8 v; __half2 h2[4]; };

// DPP 16-lane row reduction (rows of 16 = our q-groups). All VALU, no DS.
template <int CTRL>
__device__ __forceinline__ float dppadd(float x) {
  int s = __builtin_amdgcn_update_dpp(0, __float_as_int(x), CTRL, 0xF, 0xF, true);
  return x + __int_as_float(s);
}
__device__ __forceinline__ float row16_sum(float x) {
  x = dppadd<0xB1>(x);    // quad_perm [1,0,3,2]  : lane ^ 1
  x = dppadd<0x4E>(x);    // quad_perm [2,3,0,1]  : lane ^ 2
  x = dppadd<0x141>(x);   // row_half_mirror
  x = dppadd<0x140>(x);   // row_mirror
  return x;
}

// fp32x8 (two float4) -> 8 packed RNE fp16. Same numerics as the old prep
// kernel's __float2half path, just relocated into the consumer.
__device__ __forceinline__ void cvt8(const float4& lo, const float4& hi, AB& o) {
  o.h2[0] = __floats2half2_rn(lo.x, lo.y);
  o.h2[1] = __floats2half2_rn(lo.z, lo.w);
  o.h2[2] = __floats2half2_rn(hi.x, hi.y);
  o.h2[3] = __floats2half2_rn(hi.z, hi.w);
}

// ---------------------------------------------------------------------------
// Compute a PAIR of 16-edge tiles with B-fragment reuse: each of the 16
// B-frags is ds_read ONCE per pair and feeds both tiles' MFMAs. A-frags
// arrive as fp32 float4 pairs (gathered), converted to fp16 here; c,p via
// packed-fp16 VALU. Bias as MFMA C-input; fused layer-2, DPP row-reduce,
// sigmoid, guarded writes. ebase pre-clamped so ebase+31 < nE for reads;
// store guards keep writes exact.
// ---------------------------------------------------------------------------
__device__ __forceinline__ void compute_pair(
    const float4& u0L, const float4& u0H, const float4& u1L, const float4& u1H,
    const float4& v0L, const float4& v0H, const float4& v1L, const float4& v1H,
    const _Float16* __restrict__ bl,
    const float* __restrict__ b1v, const float* __restrict__ w2v, float bias2,
    int ebase, int q, int m, int nE, float* __restrict__ out) {
  AB mu0, mv0, mu1, mv1, ac0, ap0, ac1, ap1;
  cvt8(u0L, u0H, mu0); cvt8(u1L, u1H, mu1);
  cvt8(v0L, v0H, mv0); cvt8(v1L, v1H, mv1);
#pragma unroll
  for (int k = 0; k < 4; ++k) {
    ac0.h2[k] = __habs2(__hsub2(mu0.h2[k], mv0.h2[k]));
    ap0.h2[k] = __hmul2(mu0.h2[k], mv0.h2[k]);
    ac1.h2[k] = __habs2(__hsub2(mu1.h2[k], mv1.h2[k]));
    ap1.h2[k] = __hmul2(mu1.h2[k], mv1.h2[k]);
  }

  float part0[4], part1[4];
#pragma unroll
  for (int t = 0; t < 4; ++t) {
    float bv = b1v[t];
    f32x4 acc0 = (f32x4){bv, bv, bv, bv};
    f32x4 acc1 = (f32x4){bv, bv, bv, bv};
    // one ds_read per fragment, two MFMAs (both tiles)
    f16x8 B0 = *(const f16x8*)(bl + (t * 4 + 0) * 512);
    acc0 = __builtin_amdgcn_mfma_f32_16x16x32_f16(mu0.v, B0, acc0, 0, 0, 0);
    acc1 = __builtin_amdgcn_mfma_f32_16x16x32_f16(mu1.v, B0, acc1, 0, 0, 0);
    f16x8 B1 = *(const f16x8*)(bl + (t * 4 + 1) * 512);
    acc0 = __builtin_amdgcn_mfma_f32_16x16x32_f16(mv0.v, B1, acc0, 0, 0, 0);
    acc1 = __builtin_amdgcn_mfma_f32_16x16x32_f16(mv1.v, B1, acc1, 0, 0, 0);
    f16x8 B2 = *(const f16x8*)(bl + (t * 4 + 2) * 512);
    acc0 = __builtin_amdgcn_mfma_f32_16x16x32_f16(ac0.v, B2, acc0, 0, 0, 0);
    acc1 = __builtin_amdgcn_mfma_f32_16x16x32_f16(ac1.v, B2, acc1, 0, 0, 0);
    f16x8 B3 = *(const f16x8*)(bl + (t * 4 + 3) * 512);
    acc0 = __builtin_amdgcn_mfma_f32_16x16x32_f16(ap0.v, B3, acc0, 0, 0, 0);
    acc1 = __builtin_amdgcn_mfma_f32_16x16x32_f16(ap1.v, B3, acc1, 0, 0, 0);
#pragma unroll
    for (int r = 0; r < 4; ++r) {
      float h0 = fmaxf(acc0[r], 0.f);
      float h1 = fmaxf(acc1[r], 0.f);
      part0[r] = (t == 0) ? h0 * w2v[0] : fmaf(h0, w2v[t], part0[r]);
      part1[r] = (t == 0) ? h1 * w2v[0] : fmaf(h1, w2v[t], part1[r]);
    }
  }

#pragma unroll
  for (int r = 0; r < 4; ++r) {
    part0[r] = row16_sum(part0[r]);
    part1[r] = row16_sum(part1[r]);
  }

  if (m < 4) {
    float z0 = (m == 0 ? part0[0] : m == 1 ? part0[1] : m == 2 ? part0[2] : part0[3]) + bias2;
    float z1 = (m == 0 ? part1[0] : m == 1 ? part1[1] : m == 2 ? part1[2] : part1[3]) + bias2;
    int ew0 = ebase + q * 4 + m;
    int ew1 = ebase + 16 + q * 4 + m;
    if (ew0 < nE) out[ew0] = 1.f / (1.f + __expf(-z0));
    if (ew1 < nE) out[ew1] = 1.f / (1.f + __expf(-z1));
  }
}

// ---------------------------------------------------------------------------
// FULLY FUSED, ZERO-WORKSPACE kernel. R1 counters showed the harness
// re-poisons the 256 MiB workspace with a ~47 us fillBuffer per iteration
// when d_ws is used -- larger than our entire kernel budget. This version
// touches no workspace:
//  * B-table (16 KB) is built in LDS per block straight from W1: coalesced
//    W1 reads (linear w -> (f,l,j) index math inverted from old prep),
//    one-time scattered ds_writes, then __syncthreads.
//  * x is gathered as fp32 (2x float4 per node-quarter) and converted to
//    RNE fp16 in-register in compute_pair (identical numerics to old prep).
// Loop structure unchanged from the proven R1 kernel: pairs of 16-edge
// tiles, x2 hand unroll, direct saddr idx loads prefetched 2 pairs ahead,
// gathers 1 pair ahead, uniform clamp to nE-32, integer-offset anti-LICM
// opacifier.
// __launch_bounds__(256,4): 128-VGPR cap. R1 LESSON: (256,8) forced a
// 64-VGPR cap -> allocator spilled (FETCH 90->430 MB, 3.4x slower). Live
// state here ~105 VGPR (two fp32 gather sets = 64); do NOT pin tighter.
// ---------------------------------------------------------------------------
__global__ __launch_bounds__(256, 4) void edge_fused(
    const float* __restrict__ x, const int* __restrict__ ei,
    const float* __restrict__ W1, const float* __restrict__ b1,
    const float* __restrict__ W2, const float* __restrict__ b2,
    float* __restrict__ out, int nE, int nPairs) {
  __shared__ _Float16 lds_b[16 * 64 * 8];   // 16 KB

  // Build B-fragment table from W1 [128][64] row-major.
  // Forward map (old prep): frag f=t*4+s, lane l, elem j  <-  W1[k][n],
  //   k = s*32 + (l>>4)*8 + j,  n = t*16 + (l&15).
  // Inverse (linear w = k*64 + n): s=k>>5, j=k&7, lh=(k&31)>>3, t=n>>4,
  //   ll=n&15, f=t*4+s, l=lh*16+ll, id = f*512 + l*8 + j.
#pragma unroll
  for (int i = 0; i < 32; ++i) {
    int w = i * 256 + threadIdx.x;        // coalesced over W1's 8192 floats
    int k = w >> 6, n = w & 63;
    int s = k >> 5, j = k & 7, lh = (k & 31) >> 3;
    int t = n >> 4, ll = n & 15;
    int id = (t * 4 + s) * 512 + (lh * 16 + ll) * 8 + j;
    lds_b[id] = (_Float16)W1[w];          // RNE, same as __float2half
  }
  __syncthreads();

  int lane = threadIdx.x & 63;
  int wid  = (blockIdx.x * 256 + threadIdx.x) >> 6;
  int nW   = (gridDim.x * 256) >> 6;
  int m = lane & 15;        // edge-in-tile (A rows) / hidden-in-tile (C cols)
  int q = lane >> 4;        // quad
  if (wid >= nPairs) return;

  float b1v[4], w2v[4];
#pragma unroll
  for (int t = 0; t < 4; ++t) {
    b1v[t] = b1[t * 16 + m];
    w2v[t] = W2[t * 16 + m];
  }
  float bias2 = b2[0];

  const float4* xb = (const float4*)x;   // node row = 8 float4; lane reads row*8 + q*2 (+1)
  const int* eis = ei;                   // src ids
  const int* eid = ei + nE;              // dst ids
  int pLim = nPairs - 1;
  int eCap = nE - 32;                    // launcher guarantees nE >= 32
  int q2 = q * 2;

  // ---- prologue: gathers for pair wid, idx for pair wid+nW ----
  int p = wid;
  int pbC = p * 32; pbC = pbC < eCap ? pbC : eCap;
  float4 au0L, au0H, au1L, au1H, av0L, av0H, av1L, av1H;
  {
    int o0 = pbC + m;
    int ia = eis[o0], ib = eis[o0 + 16], ic = eid[o0], id_ = eid[o0 + 16];
    au0L = xb[ia * 8 + q2]; au0H = xb[ia * 8 + q2 + 1];
    au1L = xb[ib * 8 + q2]; au1H = xb[ib * 8 + q2 + 1];
    av0L = xb[ic * 8 + q2]; av0H = xb[ic * 8 + q2 + 1];
    av1L = xb[id_ * 8 + q2]; av1H = xb[id_ * 8 + q2 + 1];
  }
  int ja, jb, jc, jd;
  int pbN;
  {
    int p1 = p + nW; p1 = p1 < pLim ? p1 : pLim;
    pbN = p1 * 32; pbN = pbN < eCap ? pbN : eCap;
    int o1 = pbN + m;
    ja = eis[o1]; jb = eis[o1 + 16]; jc = eid[o1]; jd = eid[o1 + 16];
  }

  float4 bu0L, bu0H, bu1L, bu1H, bv0L, bv0H, bv1L, bv1H;
  while (true) {
    // ---- step A: compute A-set, prefetch gathers into B-set ----
    bu0L = xb[ja * 8 + q2]; bu0H = xb[ja * 8 + q2 + 1];
    bu1L = xb[jb * 8 + q2]; bu1H = xb[jb * 8 + q2 + 1];
    bv0L = xb[jc * 8 + q2]; bv0H = xb[jc * 8 + q2 + 1];
    bv1L = xb[jd * 8 + q2]; bv1H = xb[jd * 8 + q2 + 1];
    int pb2;
    {
      int p2 = p + 2 * nW; p2 = p2 < pLim ? p2 : pLim;
      pb2 = p2 * 32; pb2 = pb2 < eCap ? pb2 : eCap;
      int o2 = pb2 + m;
      ja = eis[o2]; jb = eis[o2 + 16]; jc = eid[o2]; jd = eid[o2 + 16];
    }
    {
      int bofs = lane * 8;
      asm volatile("" : "+v"(bofs));
      compute_pair(au0L, au0H, au1L, au1H, av0L, av0H, av1L, av1H,
                   lds_b + bofs, b1v, w2v, bias2, pbC, q, m, nE, out);
    }
    p += nW; if (p > pLim) return;
    pbC = pbN; pbN = pb2;

    // ---- step B: compute B-set, prefetch gathers into A-set ----
    au0L = xb[ja * 8 + q2]; au0H = xb[ja * 8 + q2 + 1];
    au1L = xb[jb * 8 + q2]; au1H = xb[jb * 8 + q2 + 1];
    av0L = xb[jc * 8 + q2]; av0H = xb[jc * 8 + q2 + 1];
    av1L = xb[jd * 8 + q2]; av1H = xb[jd * 8 + q2 + 1];
    {
      int p2 = p + 2 * nW; p2 = p2 < pLim ? p2 : pLim;
      pb2 = p2 * 32; pb2 = pb2 < eCap ? pb2 : eCap;
      int o2 = pb2 + m;
      ja = eis[o2]; jb = eis[o2 + 16]; jc = eid[o2]; jd = eid[o2 + 16];
    }
    {
      int bofs = lane * 8;
      asm volatile("" : "+v"(bofs));
      compute_pair(bu0L, bu0H, bu1L, bu1H, bv0L, bv0H, bv1L, bv1H,
                   lds_b + bofs, b1v, w2v, bias2, pbC, q, m, nE, out);
    }
    p += nW; if (p > pLim) return;
    pbC = pbN; pbN = pb2;
  }
}

// ---------------------------------------------------------------------------
// Fallback (nE < 32): all-fp32 per edge.
// ---------------------------------------------------------------------------
__global__ __launch_bounds__(256) void edge_full(
    const float* __restrict__ x, const int* __restrict__ ei,
    const float* __restrict__ W1, const float* __restrict__ b1,
    const float* __restrict__ W2, const float* __restrict__ b2,
    float* __restrict__ out, int nE) {
  int e = blockIdx.x * 256 + threadIdx.x;
  if (e >= nE) return;
  int s = ei[e];
  int d = ei[e + nE];
  const float4* mu4 = (const float4*)(x + (size_t)s * D);
  const float4* mv4 = (const float4*)(x + (size_t)d * D);
  float mu[D], mv[D], c[D], p[D];
#pragma unroll
  for (int qq = 0; qq < D / 4; ++qq) {
    float4 a = mu4[qq];
    float4 b = mv4[qq];
    mu[4*qq+0] = a.x; mv[4*qq+0] = b.x; c[4*qq+0] = fabsf(a.x-b.x); p[4*qq+0] = a.x*b.x;
    mu[4*qq+1] = a.y; mv[4*qq+1] = b.y; c[4*qq+1] = fabsf(a.y-b.y); p[4*qq+1] = a.y*b.y;
    mu[4*qq+2] = a.z; mv[4*qq+2] = b.z; c[4*qq+2] = fabsf(a.z-b.z); p[4*qq+2] = a.z*b.z;
    mu[4*qq+3] = a.w; mv[4*qq+3] = b.w; c[4*qq+3] = fabsf(a.w-b.w); p[4*qq+3] = a.w*b.w;
  }
  float z = b2[0];
  for (int j = 0; j < H; ++j) {
    float a = b1[j];
#pragma unroll
    for (int k = 0; k < D; ++k) {
      a = fmaf(mu[k], W1[k * H + j], a);
      a = fmaf(mv[k], W1[(D + k) * H + j], a);
      a = fmaf(c[k],  W1[(2 * D + k) * H + j], a);
      a = fmaf(p[k],  W1[(3 * D + k) * H + j], a);
    }
    a = fmaxf(a, 0.f);
    z = fmaf(a, W2[j], z);
  }
  float g = 1.f / (1.f + __expf(-z));
  out[e] = fminf(fmaxf(g, 0.f), 1.f);
}

extern "C" void kernel_launch(void* const* d_in, const int* in_sizes, int n_in,
                              void* d_out, int out_size, void* d_ws, size_t ws_size,
                              hipStream_t stream) {
  const float* x  = (const float*)d_in[0];
  const int*   ei = (const int*)d_in[1];
  const float* W1 = (const float*)d_in[2];
  const float* b1 = (const float*)d_in[3];
  const float* W2 = (const float*)d_in[4];
  const float* b2 = (const float*)d_in[5];
  float* out = (float*)d_out;

  int nE = in_sizes[1] / 2;      // 1600000
  (void)d_ws; (void)ws_size;     // deliberately unused: ws use drags a
                                 // ~47us 256MiB poison-fill into the window

  if (nE >= 32) {
    int nTiles = (nE + 15) / 16;
    int nPairs = (nTiles + 1) / 2;
    // 4 waves/block x 4 pairs/wave: exact balance for nPairs=50000 (3125 blocks)
    int blocks = (nPairs + 15) / 16;
    if (blocks < 1) blocks = 1;
    edge_fused<<<blocks, 256, 0, stream>>>(x, ei, W1, b1, W2, b2, out, nE, nPairs);
  } else {
    edge_full<<<(nE + 255) / 256, 256, 0, stream>>>(x, ei, W1, b1, W2, b2, out, nE);
  }
}

// Round 5
// 124.340 us; speedup vs baseline: 1.8273x; 1.1359x over previous
//
#include <hip/hip_runtime.h>
#include <hip/hip_fp16.h>

#define D 32          // MOTIF_DIM
#define H 64          // HIDDEN

typedef __attribute__((ext_vector_type(8))) _Float16 f16x8;
typedef __attribute__((ext_vector_type(4))) float f32x4;

union AB { uint4 u; f16x8 v; __half2 h2[4]; };

// DPP 16-lane row reduction (rows of 16 = our q-groups). All VALU, no DS.
template <int CTRL>
__device__ __forceinline__ float dppadd(float x) {
  int s = __builtin_amdgcn_update_dpp(0, __float_as_int(x), CTRL, 0xF, 0xF, true);
  return x + __int_as_float(s);
}
__device__ __forceinline__ float row16_sum(float x) {
  x = dppadd<0xB1>(x);    // quad_perm [1,0,3,2]  : lane ^ 1
  x = dppadd<0x4E>(x);    // quad_perm [2,3,0,1]  : lane ^ 2
  x = dppadd<0x141>(x);   // row_half_mirror
  x = dppadd<0x140>(x);   // row_mirror
  return x;
}

// ---------------------------------------------------------------------------
// Fused prep: blocks [0, nPack) convert x fp32 -> fp16 rows (RNE);
// remaining blocks build the W1 B-fragment table in fp16 (16 frags x 64
// lanes x 8 = 16 KB). Frag f = t*4+s: lane l elem j = W1[s*32+(l>>4)*8+j][t*16+(l&15)].
// ---------------------------------------------------------------------------
__global__ __launch_bounds__(256) void prep(
    const float* __restrict__ x, const float* __restrict__ W1,
    unsigned short* __restrict__ xh, unsigned short* __restrict__ btab,
    int n4, int nPack) {
  int b = blockIdx.x;
  if (b < nPack) {
    int i = b * 256 + threadIdx.x;
    if (i < n4) {
      float4 v = ((const float4*)x)[i];
      ushort4 o;
      o.x = __half_as_ushort(__float2half(v.x));
      o.y = __half_as_ushort(__float2half(v.y));
      o.z = __half_as_ushort(__float2half(v.z));
      o.w = __half_as_ushort(__float2half(v.w));
      ((ushort4*)xh)[i] = o;
    }
  } else {
    int id = (b - nPack) * 256 + threadIdx.x;      // 0..8191
    if (id < 16 * 64 * 8) {
      int j = id & 7;
      int l = (id >> 3) & 63;
      int f = id >> 9;
      int s = f & 3, t = f >> 2;
      int k = s * 32 + (l >> 4) * 8 + j;
      int n = t * 16 + (l & 15);
      btab[id] = __half_as_ushort(__float2half(W1[k * H + n]));
    }
  }
}

// ---------------------------------------------------------------------------
// Compute a PAIR of 16-edge tiles with B-fragment reuse: each of the 16
// B-frags is ds_read ONCE per pair and feeds both tiles' MFMAs. A-frags:
// mu,mv gathered fp16; c,p via packed-fp16 VALU. Bias as MFMA C-input;
// fused layer-2, DPP row-reduce, sigmoid, guarded writes. ebase pre-clamped
// so ebase+31 < nE for reads; store guards keep writes exact.
// ---------------------------------------------------------------------------
__device__ __forceinline__ void compute_pair(
    uint4 mu0U, uint4 mv0U, uint4 mu1U, uint4 mv1U,
    const _Float16* __restrict__ bl,
    const float* __restrict__ b1v, const float* __restrict__ w2v, float bias2,
    int ebase, int q, int m, int nE, float* __restrict__ out) {
  AB mu0, mv0, mu1, mv1, ac0, ap0, ac1, ap1;
  mu0.u = mu0U; mv0.u = mv0U; mu1.u = mu1U; mv1.u = mv1U;
#pragma unroll
  for (int k = 0; k < 4; ++k) {
    ac0.h2[k] = __habs2(__hsub2(mu0.h2[k], mv0.h2[k]));
    ap0.h2[k] = __hmul2(mu0.h2[k], mv0.h2[k]);
    ac1.h2[k] = __habs2(__hsub2(mu1.h2[k], mv1.h2[k]));
    ap1.h2[k] = __hmul2(mu1.h2[k], mv1.h2[k]);
  }

  float part0[4], part1[4];
#pragma unroll
  for (int t = 0; t < 4; ++t) {
    float bv = b1v[t];
    f32x4 acc0 = (f32x4){bv, bv, bv, bv};
    f32x4 acc1 = (f32x4){bv, bv, bv, bv};
    // one ds_read per fragment, two MFMAs (both tiles)
    f16x8 B0 = *(const f16x8*)(bl + (t * 4 + 0) * 512);
    acc0 = __builtin_amdgcn_mfma_f32_16x16x32_f16(mu0.v, B0, acc0, 0, 0, 0);
    acc1 = __builtin_amdgcn_mfma_f32_16x16x32_f16(mu1.v, B0, acc1, 0, 0, 0);
    f16x8 B1 = *(const f16x8*)(bl + (t * 4 + 1) * 512);
    acc0 = __builtin_amdgcn_mfma_f32_16x16x32_f16(mv0.v, B1, acc0, 0, 0, 0);
    acc1 = __builtin_amdgcn_mfma_f32_16x16x32_f16(mv1.v, B1, acc1, 0, 0, 0);
    f16x8 B2 = *(const f16x8*)(bl + (t * 4 + 2) * 512);
    acc0 = __builtin_amdgcn_mfma_f32_16x16x32_f16(ac0.v, B2, acc0, 0, 0, 0);
    acc1 = __builtin_amdgcn_mfma_f32_16x16x32_f16(ac1.v, B2, acc1, 0, 0, 0);
    f16x8 B3 = *(const f16x8*)(bl + (t * 4 + 3) * 512);
    acc0 = __builtin_amdgcn_mfma_f32_16x16x32_f16(ap0.v, B3, acc0, 0, 0, 0);
    acc1 = __builtin_amdgcn_mfma_f32_16x16x32_f16(ap1.v, B3, acc1, 0, 0, 0);
#pragma unroll
    for (int r = 0; r < 4; ++r) {
      float h0 = fmaxf(acc0[r], 0.f);
      float h1 = fmaxf(acc1[r], 0.f);
      part0[r] = (t == 0) ? h0 * w2v[0] : fmaf(h0, w2v[t], part0[r]);
      part1[r] = (t == 0) ? h1 * w2v[0] : fmaf(h1, w2v[t], part1[r]);
    }
  }

#pragma unroll
  for (int r = 0; r < 4; ++r) {
    part0[r] = row16_sum(part0[r]);
    part1[r] = row16_sum(part1[r]);
  }

  if (m < 4) {
    float z0 = (m == 0 ? part0[0] : m == 1 ? part0[1] : m == 2 ? part0[2] : part0[3]) + bias2;
    float z1 = (m == 0 ? part1[0] : m == 1 ? part1[1] : m == 2 ? part1[2] : part1[3]) + bias2;
    int ew0 = ebase + q * 4 + m;
    int ew1 = ebase + 16 + q * 4 + m;
    if (ew0 < nE) out[ew0] = 1.f / (1.f + __expf(-z0));
    if (ew1 < nE) out[ew1] = 1.f / (1.f + __expf(-z1));
  }
}

// ---------------------------------------------------------------------------
// Main: pairs of consecutive 16-edge tiles per wave, grid-stride, unrolled
// x3 with THREE rotating gather sets (S0/S1/S2) and THREE idx quads
// (I0/I1/I2). Gathers are issued TWO pairs ahead of use (~700+ cyc cover
// for HBM-latency gathers; R2 depth was one pair = ~350 cyc, only enough
// for L2 hits). idx loads are issued three pairs ahead. All set indices
// static (period-3 unroll), no rotation movs. Pair base recomputed per
// step (2 ALU) and uniformly clamped to nE-32; tail recompute idempotent.
// B table staged into LDS with coalesced uint4 copies (ZERO bank
// conflicts; R4 lesson: the scattered in-kernel build costs 2.4M).
// __launch_bounds__(256,4): 128-VGPR cap; est. live ~115. R1 LESSON:
// (256,8) forced 64-cap -> spill catastrophe. Do NOT pin tighter.
// R4 LESSON: the 256MiB ws poison fill is UNCONDITIONAL (runs even with
// ws untouched) -- ws use is free; fp16 prep stays.
// ---------------------------------------------------------------------------
__global__ __launch_bounds__(256, 4) void edge_mfma(
    const unsigned short* __restrict__ xh, const unsigned short* __restrict__ btab,
    const int* __restrict__ ei,
    const float* __restrict__ b1, const float* __restrict__ W2,
    const float* __restrict__ b2, float* __restrict__ out,
    int nE, int nPairs) {
  __shared__ _Float16 lds_b[16 * 64 * 8];   // 16 KB

  // stage B table: 1024 uint4, 256 threads x 4 (coalesced)
  {
    const uint4* src = (const uint4*)btab;
    uint4* dst = (uint4*)lds_b;
#pragma unroll
    for (int i = 0; i < 4; ++i)
      dst[threadIdx.x + i * 256] = src[threadIdx.x + i * 256];
  }
  __syncthreads();

  int lane = threadIdx.x & 63;
  int wid  = (blockIdx.x * 256 + threadIdx.x) >> 6;
  int nW   = (gridDim.x * 256) >> 6;
  int m = lane & 15;        // edge-in-tile (A rows) / hidden-in-tile (C cols)
  int q = lane >> 4;        // quad
  if (wid >= nPairs) return;

  float b1v[4], w2v[4];
#pragma unroll
  for (int t = 0; t < 4; ++t) {
    b1v[t] = b1[t * 16 + m];
    w2v[t] = W2[t * 16 + m];
  }
  float bias2 = b2[0];

  const uint4* xb = (const uint4*)xh;    // node row = 4 uint4; lane reads row*4+q
  const int* eis = ei;                   // src ids
  const int* eid = ei + nE;              // dst ids
  int pLim = nPairs - 1;
  int eCap = nE - 32;                    // launcher guarantees nE >= 32

  // idx quads for pairs k, k+1, k+2 (mod-3 rotation, static names)
  int i0a, i0b, i0c, i0d, i1a, i1b, i1c, i1d, i2a, i2b, i2c, i2d;
  // gather sets
  uint4 s0u0, s0u1, s0v0, s0v1, s1u0, s1u1, s1v0, s1v1, s2u0, s2u1, s2v0, s2v1;

  int p = wid;
  {
    int b0 = p * 32; b0 = b0 < eCap ? b0 : eCap;
    int o = b0 + m;
    i0a = eis[o]; i0b = eis[o + 16]; i0c = eid[o]; i0d = eid[o + 16];
  }
  {
    int p1 = p + nW; p1 = p1 < pLim ? p1 : pLim;
    int bb = p1 * 32; bb = bb < eCap ? bb : eCap;
    int o = bb + m;
    i1a = eis[o]; i1b = eis[o + 16]; i1c = eid[o]; i1d = eid[o + 16];
  }
  {
    int p2 = p + 2 * nW; p2 = p2 < pLim ? p2 : pLim;
    int bb = p2 * 32; bb = bb < eCap ? bb : eCap;
    int o = bb + m;
    i2a = eis[o]; i2b = eis[o + 16]; i2c = eid[o]; i2d = eid[o + 16];
  }
  // gathers for pair k (S0) and k+1 (S1)
  s0u0 = xb[i0a * 4 + q]; s0u1 = xb[i0b * 4 + q];
  s0v0 = xb[i0c * 4 + q]; s0v1 = xb[i0d * 4 + q];
  s1u0 = xb[i1a * 4 + q]; s1u1 = xb[i1b * 4 + q];
  s1v0 = xb[i1c * 4 + q]; s1v1 = xb[i1d * 4 + q];

  // STEP(cur-set, prefetch-set, prefetch-idx, reload-idx):
  //  1. issue gathers for pair p+2 into prefetch-set (ids in prefetch-idx)
  //  2. load idx for pair p+3 into reload-idx (just consumed)
  //  3. compute current pair from cur-set
  //  4. advance; exit when past last
#define STEP(CU0, CU1, CV0, CV1, PU0, PU1, PV0, PV1, PA, PB, PC, PD, RA, RB, RC, RD) \
  {                                                                         \
    PU0 = xb[PA * 4 + q]; PU1 = xb[PB * 4 + q];                             \
    PV0 = xb[PC * 4 + q]; PV1 = xb[PD * 4 + q];                             \
    int pf = p + 3 * nW; pf = pf < pLim ? pf : pLim;                        \
    int bf = pf * 32; bf = bf < eCap ? bf : eCap;                           \
    int of = bf + m;                                                        \
    RA = eis[of]; RB = eis[of + 16]; RC = eid[of]; RD = eid[of + 16];       \
    int eb = p * 32; eb = eb < eCap ? eb : eCap;                            \
    int bofs = lane * 8;                                                    \
    asm volatile("" : "+v"(bofs));                                          \
    compute_pair(CU0, CV0, CU1, CV1, lds_b + bofs, b1v, w2v, bias2,         \
                 eb, q, m, nE, out);                                        \
    p += nW; if (p > pLim) return;                                          \
  }

  while (true) {
    // compute S0 (pair k)  : prefetch S2 <- I2 (pair k+2), reload I0 (pair k+3)
    STEP(s0u0, s0u1, s0v0, s0v1, s2u0, s2u1, s2v0, s2v1,
         i2a, i2b, i2c, i2d, i0a, i0b, i0c, i0d)
    // compute S1 (pair k+1): prefetch S0 <- I0 (pair k+3), reload I1 (pair k+4)
    STEP(s1u0, s1u1, s1v0, s1v1, s0u0, s0u1, s0v0, s0v1,
         i0a, i0b, i0c, i0d, i1a, i1b, i1c, i1d)
    // compute S2 (pair k+2): prefetch S1 <- I1 (pair k+4), reload I2 (pair k+5)
    STEP(s2u0, s2u1, s2v0, s2v1, s1u0, s1u1, s1v0, s1v1,
         i1a, i1b, i1c, i1d, i2a, i2b, i2c, i2d)
  }
#undef STEP
}

// ---------------------------------------------------------------------------
// Fallback (ws too small or nE < 32): all-fp32 per edge, no workspace needed.
// ---------------------------------------------------------------------------
__global__ __launch_bounds__(256) void edge_full(
    const float* __restrict__ x, const int* __restrict__ ei,
    const float* __restrict__ W1, const float* __restrict__ b1,
    const float* __restrict__ W2, const float* __restrict__ b2,
    float* __restrict__ out, int nE) {
  int e = blockIdx.x * 256 + threadIdx.x;
  if (e >= nE) return;
  int s = ei[e];
  int d = ei[e + nE];
  const float4* mu4 = (const float4*)(x + (size_t)s * D);
  const float4* mv4 = (const float4*)(x + (size_t)d * D);
  float mu[D], mv[D], c[D], p[D];
#pragma unroll
  for (int qq = 0; qq < D / 4; ++qq) {
    float4 a = mu4[qq];
    float4 b = mv4[qq];
    mu[4*qq+0] = a.x; mv[4*qq+0] = b.x; c[4*qq+0] = fabsf(a.x-b.x); p[4*qq+0] = a.x*b.x;
    mu[4*qq+1] = a.y; mv[4*qq+1] = b.y; c[4*qq+1] = fabsf(a.y-b.y); p[4*qq+1] = a.y*b.y;
    mu[4*qq+2] = a.z; mv[4*qq+2] = b.z; c[4*qq+2] = fabsf(a.z-b.z); p[4*qq+2] = a.z*b.z;
    mu[4*qq+3] = a.w; mv[4*qq+3] = b.w; c[4*qq+3] = fabsf(a.w-b.w); p[4*qq+3] = a.w*b.w;
  }
  float z = b2[0];
  for (int j = 0; j < H; ++j) {
    float a = b1[j];
#pragma unroll
    for (int k = 0; k < D; ++k) {
      a = fmaf(mu[k], W1[k * H + j], a);
      a = fmaf(mv[k], W1[(D + k) * H + j], a);
      a = fmaf(c[k],  W1[(2 * D + k) * H + j], a);
      a = fmaf(p[k],  W1[(3 * D + k) * H + j], a);
    }
    a = fmaxf(a, 0.f);
    z = fmaf(a, W2[j], z);
  }
  float g = 1.f / (1.f + __expf(-z));
  out[e] = fminf(fmaxf(g, 0.f), 1.f);
}

extern "C" void kernel_launch(void* const* d_in, const int* in_sizes, int n_in,
                              void* d_out, int out_size, void* d_ws, size_t ws_size,
                              hipStream_t stream) {
  const float* x  = (const float*)d_in[0];
  const int*   ei = (const int*)d_in[1];
  const float* W1 = (const float*)d_in[2];
  const float* b1 = (const float*)d_in[3];
  const float* W2 = (const float*)d_in[4];
  const float* b2 = (const float*)d_in[5];
  float* out = (float*)d_out;

  int nN = in_sizes[0] / D;      // 100000
  int nE = in_sizes[1] / 2;      // 1600000

  size_t xh_shorts = (size_t)nN * D;                      // 6.4 MB
  size_t need = (xh_shorts + 16 * 64 * 8) * sizeof(unsigned short);
  if (ws_size >= need && nE >= 32) {
    unsigned short* xh   = (unsigned short*)d_ws;
    unsigned short* btab = xh + xh_shorts;
    int n4 = nN * D / 4;
    int nPack = (n4 + 255) / 256;
    int nBt = (16 * 64 * 8 + 255) / 256;
    prep<<<nPack + nBt, 256, 0, stream>>>(x, W1, xh, btab, n4, nPack);
    int nTiles = (nE + 15) / 16;
    int nPairs = (nTiles + 1) / 2;
    // 4 waves/block x 4 pairs/wave: exact balance for nPairs=50000 (3125 blocks)
    int blocks = (nPairs + 15) / 16;
    if (blocks < 1) blocks = 1;
    edge_mfma<<<blocks, 256, 0, stream>>>(xh, btab, ei, b1, W2, b2, out, nE, nPairs);
  } else {
    edge_full<<<(nE + 255) / 256, 256, 0, stream>>>(x, ei, W1, b1, W2, b2, out, nE);
  }
}

// Round 6
// 120.854 us; speedup vs baseline: 1.8800x; 1.0288x over previous
//
#include <hip/hip_runtime.h>
#include <hip/hip_fp16.h>

#define D 32          // MOTIF_DIM
#define H 64          // HIDDEN

typedef __attribute__((ext_vector_type(8))) _Float16 f16x8;
typedef __attribute__((ext_vector_type(4))) float f32x4;
typedef __attribute__((ext_vector_type(2))) float f32x2;

union AB { uint4 u; f16x8 v; __half2 h2[4]; };

// DPP 16-lane row reduction (rows of 16 = our q-groups). All VALU, no DS.
// update_dpp(0,...,0xF,0xF,true)+fadd is the canonical GCNDPPCombine-foldable
// pattern -> v_add_f32_dpp.
template <int CTRL>
__device__ __forceinline__ float dppadd(float x) {
  int s = __builtin_amdgcn_update_dpp(0, __float_as_int(x), CTRL, 0xF, 0xF, true);
  return x + __int_as_float(s);
}
__device__ __forceinline__ float row16_sum(float x) {
  x = dppadd<0xB1>(x);    // quad_perm [1,0,3,2]  : lane ^ 1
  x = dppadd<0x4E>(x);    // quad_perm [2,3,0,1]  : lane ^ 2
  x = dppadd<0x141>(x);   // row_half_mirror
  x = dppadd<0x140>(x);   // row_mirror
  return x;
}

// ---------------------------------------------------------------------------
// Fused prep: blocks [0, nPack) convert x fp32 -> fp16 rows (RNE);
// remaining blocks build the W1 B-fragment table in fp16 (16 frags x 64
// lanes x 8 = 16 KB). Frag f = t*4+s: lane l elem j = W1[s*32+(l>>4)*8+j][t*16+(l&15)].
// ---------------------------------------------------------------------------
__global__ __launch_bounds__(256) void prep(
    const float* __restrict__ x, const float* __restrict__ W1,
    unsigned short* __restrict__ xh, unsigned short* __restrict__ btab,
    int n4, int nPack) {
  int b = blockIdx.x;
  if (b < nPack) {
    int i = b * 256 + threadIdx.x;
    if (i < n4) {
      float4 v = ((const float4*)x)[i];
      ushort4 o;
      o.x = __half_as_ushort(__float2half(v.x));
      o.y = __half_as_ushort(__float2half(v.y));
      o.z = __half_as_ushort(__float2half(v.z));
      o.w = __half_as_ushort(__float2half(v.w));
      ((ushort4*)xh)[i] = o;
    }
  } else {
    int id = (b - nPack) * 256 + threadIdx.x;      // 0..8191
    if (id < 16 * 64 * 8) {
      int j = id & 7;
      int l = (id >> 3) & 63;
      int f = id >> 9;
      int s = f & 3, t = f >> 2;
      int k = s * 32 + (l >> 4) * 8 + j;
      int n = t * 16 + (l & 15);
      btab[id] = __half_as_ushort(__float2half(W1[k * H + n]));
    }
  }
}

// ---------------------------------------------------------------------------
// Compute a PAIR of 16-edge tiles with B-fragment reuse: each of the 16
// B-frags is ds_read ONCE per pair and feeds both tiles' MFMAs. A-frags:
// mu,mv gathered fp16; c,p via packed-fp16 VALU. Bias enters as the C
// operand of the FIRST MFMA in each chain (bvec is loop-invariant; D and C
// are separate operand fields, so no per-pair init movs). Layer-2 relu+fma
// in packed fp32 pairs (VOP3P where available). DPP row-reduce, sigmoid,
// guarded writes. ebase pre-clamped so ebase+31 < nE for reads.
// ---------------------------------------------------------------------------
__device__ __forceinline__ void compute_pair(
    uint4 mu0U, uint4 mv0U, uint4 mu1U, uint4 mv1U,
    const _Float16* __restrict__ bl,
    const f32x4* __restrict__ bvec, const f32x2* __restrict__ w2s, float bias2,
    int ebase, int q, int m, int nE, float* __restrict__ out) {
  AB mu0, mv0, mu1, mv1, ac0, ap0, ac1, ap1;
  mu0.u = mu0U; mv0.u = mv0U; mu1.u = mu1U; mv1.u = mv1U;
#pragma unroll
  for (int k = 0; k < 4; ++k) {
    ac0.h2[k] = __habs2(__hsub2(mu0.h2[k], mv0.h2[k]));
    ap0.h2[k] = __hmul2(mu0.h2[k], mv0.h2[k]);
    ac1.h2[k] = __habs2(__hsub2(mu1.h2[k], mv1.h2[k]));
    ap1.h2[k] = __hmul2(mu1.h2[k], mv1.h2[k]);
  }

  const f32x2 zero2 = {0.f, 0.f};
  f32x2 p0a, p0b, p1a, p1b;    // part0 r={0,1},{2,3}; part1 r={0,1},{2,3}
#pragma unroll
  for (int t = 0; t < 4; ++t) {
    // one ds_read per fragment, two MFMAs (both tiles); bias as C of first
    f16x8 B0 = *(const f16x8*)(bl + (t * 4 + 0) * 512);
    f32x4 acc0 = __builtin_amdgcn_mfma_f32_16x16x32_f16(mu0.v, B0, bvec[t], 0, 0, 0);
    f32x4 acc1 = __builtin_amdgcn_mfma_f32_16x16x32_f16(mu1.v, B0, bvec[t], 0, 0, 0);
    f16x8 B1 = *(const f16x8*)(bl + (t * 4 + 1) * 512);
    acc0 = __builtin_amdgcn_mfma_f32_16x16x32_f16(mv0.v, B1, acc0, 0, 0, 0);
    acc1 = __builtin_amdgcn_mfma_f32_16x16x32_f16(mv1.v, B1, acc1, 0, 0, 0);
    f16x8 B2 = *(const f16x8*)(bl + (t * 4 + 2) * 512);
    acc0 = __builtin_amdgcn_mfma_f32_16x16x32_f16(ac0.v, B2, acc0, 0, 0, 0);
    acc1 = __builtin_amdgcn_mfma_f32_16x16x32_f16(ac1.v, B2, acc1, 0, 0, 0);
    f16x8 B3 = *(const f16x8*)(bl + (t * 4 + 3) * 512);
    acc0 = __builtin_amdgcn_mfma_f32_16x16x32_f16(ap0.v, B3, acc0, 0, 0, 0);
    acc1 = __builtin_amdgcn_mfma_f32_16x16x32_f16(ap1.v, B3, acc1, 0, 0, 0);

    f32x2 h0a = {acc0[0], acc0[1]}, h0b = {acc0[2], acc0[3]};
    f32x2 h1a = {acc1[0], acc1[1]}, h1b = {acc1[2], acc1[3]};
    h0a = __builtin_elementwise_max(h0a, zero2);
    h0b = __builtin_elementwise_max(h0b, zero2);
    h1a = __builtin_elementwise_max(h1a, zero2);
    h1b = __builtin_elementwise_max(h1b, zero2);
    if (t == 0) {
      p0a = h0a * w2s[0]; p0b = h0b * w2s[0];
      p1a = h1a * w2s[0]; p1b = h1b * w2s[0];
    } else {
      p0a = __builtin_elementwise_fma(h0a, w2s[t], p0a);
      p0b = __builtin_elementwise_fma(h0b, w2s[t], p0b);
      p1a = __builtin_elementwise_fma(h1a, w2s[t], p1a);
      p1b = __builtin_elementwise_fma(h1b, w2s[t], p1b);
    }
  }

  float part0[4] = {p0a[0], p0a[1], p0b[0], p0b[1]};
  float part1[4] = {p1a[0], p1a[1], p1b[0], p1b[1]};
#pragma unroll
  for (int r = 0; r < 4; ++r) {
    part0[r] = row16_sum(part0[r]);
    part1[r] = row16_sum(part1[r]);
  }

  if (m < 4) {
    float z0 = (m == 0 ? part0[0] : m == 1 ? part0[1] : m == 2 ? part0[2] : part0[3]) + bias2;
    float z1 = (m == 0 ? part1[0] : m == 1 ? part1[1] : m == 2 ? part1[2] : part1[3]) + bias2;
    int ew0 = ebase + q * 4 + m;
    int ew1 = ebase + 16 + q * 4 + m;
    if (ew0 < nE) out[ew0] = 1.f / (1.f + __expf(-z0));
    if (ew1 < nE) out[ew1] = 1.f / (1.f + __expf(-z1));
  }
}

// ---------------------------------------------------------------------------
// Main: EXACT R2 loop structure (proven 39.7 us): pairs of consecutive
// 16-edge tiles per wave, grid-stride, x2 hand unroll, direct saddr idx
// loads prefetched 2 pairs ahead, gathers 1 pair ahead, uniform clamp to
// nE-32, integer-offset anti-LICM opacifier, coalesced B staging.
// R5 LESSON: depth-2 gather prefetch (3 rotating sets) gets de-pipelined
// by the register allocator (VGPR forced to 64, loads sunk to use) --
// depth-1 is the max the scheduler honors here. Do not deepen.
// R1 LESSON: (256,8) forced 64-VGPR cap -> spill catastrophe; keep (256,4).
// R4 LESSON: the 256MiB ws poison fill is UNCONDITIONAL; ws use is free.
// ---------------------------------------------------------------------------
__global__ __launch_bounds__(256, 4) void edge_mfma(
    const unsigned short* __restrict__ xh, const unsigned short* __restrict__ btab,
    const int* __restrict__ ei,
    const float* __restrict__ b1, const float* __restrict__ W2,
    const float* __restrict__ b2, float* __restrict__ out,
    int nE, int nPairs) {
  __shared__ _Float16 lds_b[16 * 64 * 8];   // 16 KB

  // stage B table: 1024 uint4, 256 threads x 4 (coalesced, zero conflicts)
  {
    const uint4* src = (const uint4*)btab;
    uint4* dst = (uint4*)lds_b;
#pragma unroll
    for (int i = 0; i < 4; ++i)
      dst[threadIdx.x + i * 256] = src[threadIdx.x + i * 256];
  }
  __syncthreads();

  int lane = threadIdx.x & 63;
  int wid  = (blockIdx.x * 256 + threadIdx.x) >> 6;
  int nW   = (gridDim.x * 256) >> 6;
  int m = lane & 15;        // edge-in-tile (A rows) / hidden-in-tile (C cols)
  int q = lane >> 4;        // quad
  if (wid >= nPairs) return;

  // loop-invariant bias/W2 vectors (hoisted: no per-pair init movs)
  f32x4 bvec[4];
  f32x2 w2s[4];
#pragma unroll
  for (int t = 0; t < 4; ++t) {
    float bv = b1[t * 16 + m];
    float wv = W2[t * 16 + m];
    bvec[t] = (f32x4){bv, bv, bv, bv};
    w2s[t] = (f32x2){wv, wv};
  }
  float bias2 = b2[0];

  const uint4* xb = (const uint4*)xh;    // node row = 4 uint4; lane reads row*4+q
  const int* eis = ei;                   // src ids
  const int* eid = ei + nE;              // dst ids
  int pLim = nPairs - 1;
  int eCap = nE - 32;                    // launcher guarantees nE >= 32

  // ---- prologue: gathers for pair wid, idx for pair wid+nW ----
  int p = wid;
  int pbC = p * 32; pbC = pbC < eCap ? pbC : eCap;
  uint4 amu0, amu1, amv0, amv1;
  {
    int o0 = pbC + m;
    int ia = eis[o0], ib = eis[o0 + 16], ic = eid[o0], id_ = eid[o0 + 16];
    amu0 = xb[ia * 4 + q]; amu1 = xb[ib * 4 + q];
    amv0 = xb[ic * 4 + q]; amv1 = xb[id_ * 4 + q];
  }
  int ja, jb, jc, jd;
  int pbN;
  {
    int p1 = p + nW; p1 = p1 < pLim ? p1 : pLim;
    pbN = p1 * 32; pbN = pbN < eCap ? pbN : eCap;
    int o1 = pbN + m;
    ja = eis[o1]; jb = eis[o1 + 16]; jc = eid[o1]; jd = eid[o1 + 16];
  }

  uint4 bmu0, bmu1, bmv0, bmv1;
  while (true) {
    // ---- step A: compute A-set, prefetch gathers into B-set ----
    bmu0 = xb[ja * 4 + q]; bmu1 = xb[jb * 4 + q];
    bmv0 = xb[jc * 4 + q]; bmv1 = xb[jd * 4 + q];
    int pb2;
    {
      int p2 = p + 2 * nW; p2 = p2 < pLim ? p2 : pLim;
      pb2 = p2 * 32; pb2 = pb2 < eCap ? pb2 : eCap;
      int o2 = pb2 + m;
      ja = eis[o2]; jb = eis[o2 + 16]; jc = eid[o2]; jd = eid[o2 + 16];
    }
    {
      int bofs = lane * 8;
      asm volatile("" : "+v"(bofs));
      compute_pair(amu0, amv0, amu1, amv1, lds_b + bofs, bvec, w2s, bias2,
                   pbC, q, m, nE, out);
    }
    p += nW; if (p > pLim) return;
    pbC = pbN; pbN = pb2;

    // ---- step B: compute B-set, prefetch gathers into A-set ----
    amu0 = xb[ja * 4 + q]; amu1 = xb[jb * 4 + q];
    amv0 = xb[jc * 4 + q]; amv1 = xb[jd * 4 + q];
    {
      int p2 = p + 2 * nW; p2 = p2 < pLim ? p2 : pLim;
      pb2 = p2 * 32; pb2 = pb2 < eCap ? pb2 : eCap;
      int o2 = pb2 + m;
      ja = eis[o2]; jb = eis[o2 + 16]; jc = eid[o2]; jd = eid[o2 + 16];
    }
    {
      int bofs = lane * 8;
      asm volatile("" : "+v"(bofs));
      compute_pair(bmu0, bmv0, bmu1, bmv1, lds_b + bofs, bvec, w2s, bias2,
                   pbC, q, m, nE, out);
    }
    p += nW; if (p > pLim) return;
    pbC = pbN; pbN = pb2;
  }
}

// ---------------------------------------------------------------------------
// Fallback (ws too small or nE < 32): all-fp32 per edge, no workspace needed.
// ---------------------------------------------------------------------------
__global__ __launch_bounds__(256) void edge_full(
    const float* __restrict__ x, const int* __restrict__ ei,
    const float* __restrict__ W1, const float* __restrict__ b1,
    const float* __restrict__ W2, const float* __restrict__ b2,
    float* __restrict__ out, int nE) {
  int e = blockIdx.x * 256 + threadIdx.x;
  if (e >= nE) return;
  int s = ei[e];
  int d = ei[e + nE];
  const float4* mu4 = (const float4*)(x + (size_t)s * D);
  const float4* mv4 = (const float4*)(x + (size_t)d * D);
  float mu[D], mv[D], c[D], p[D];
#pragma unroll
  for (int qq = 0; qq < D / 4; ++qq) {
    float4 a = mu4[qq];
    float4 b = mv4[qq];
    mu[4*qq+0] = a.x; mv[4*qq+0] = b.x; c[4*qq+0] = fabsf(a.x-b.x); p[4*qq+0] = a.x*b.x;
    mu[4*qq+1] = a.y; mv[4*qq+1] = b.y; c[4*qq+1] = fabsf(a.y-b.y); p[4*qq+1] = a.y*b.y;
    mu[4*qq+2] = a.z; mv[4*qq+2] = b.z; c[4*qq+2] = fabsf(a.z-b.z); p[4*qq+2] = a.z*b.z;
    mu[4*qq+3] = a.w; mv[4*qq+3] = b.w; c[4*qq+3] = fabsf(a.w-b.w); p[4*qq+3] = a.w*b.w;
  }
  float z = b2[0];
  for (int j = 0; j < H; ++j) {
    float a = b1[j];
#pragma unroll
    for (int k = 0; k < D; ++k) {
      a = fmaf(mu[k], W1[k * H + j], a);
      a = fmaf(mv[k], W1[(D + k) * H + j], a);
      a = fmaf(c[k],  W1[(2 * D + k) * H + j], a);
      a = fmaf(p[k],  W1[(3 * D + k) * H + j], a);
    }
    a = fmaxf(a, 0.f);
    z = fmaf(a, W2[j], z);
  }
  float g = 1.f / (1.f + __expf(-z));
  out[e] = fminf(fmaxf(g, 0.f), 1.f);
}

extern "C" void kernel_launch(void* const* d_in, const int* in_sizes, int n_in,
                              void* d_out, int out_size, void* d_ws, size_t ws_size,
                              hipStream_t stream) {
  const float* x  = (const float*)d_in[0];
  const int*   ei = (const int*)d_in[1];
  const float* W1 = (const float*)d_in[2];
  const float* b1 = (const float*)d_in[3];
  const float* W2 = (const float*)d_in[4];
  const float* b2 = (const float*)d_in[5];
  float* out = (float*)d_out;

  int nN = in_sizes[0] / D;      // 100000
  int nE = in_sizes[1] / 2;      // 1600000

  size_t xh_shorts = (size_t)nN * D;                      // 6.4 MB
  size_t need = (xh_shorts + 16 * 64 * 8) * sizeof(unsigned short);
  if (ws_size >= need && nE >= 32) {
    unsigned short* xh   = (unsigned short*)d_ws;
    unsigned short* btab = xh + xh_shorts;
    int n4 = nN * D / 4;
    int nPack = (n4 + 255) / 256;
    int nBt = (16 * 64 * 8 + 255) / 256;
    prep<<<nPack + nBt, 256, 0, stream>>>(x, W1, xh, btab, n4, nPack);
    int nTiles = (nE + 15) / 16;
    int nPairs = (nTiles + 1) / 2;
    // 4 waves/block x 4 pairs/wave: exact balance for nPairs=50000 (3125 blocks)
    int blocks = (nPairs + 15) / 16;
    if (blocks < 1) blocks = 1;
    edge_mfma<<<blocks, 256, 0, stream>>>(xh, btab, ei, b1, W2, b2, out, nE, nPairs);
  } else {
    edge_full<<<(nE + 255) / 256, 256, 0, stream>>>(x, ei, W1, b1, W2, b2, out, nE);
  }
}

// Round 7
// 120.458 us; speedup vs baseline: 1.8862x; 1.0033x over previous
//
#include <hip/hip_runtime.h>
#include <hip/hip_fp16.h>

#define D 32          // MOTIF_DIM
#define H 64          // HIDDEN

typedef __attribute__((ext_vector_type(8))) _Float16 f16x8;
typedef __attribute__((ext_vector_type(4))) float f32x4;

union AB { uint4 u; f16x8 v; __half2 h2[4]; };

// DPP 16-lane row reduction (rows of 16 = our q-groups). All VALU, no DS.
template <int CTRL>
__device__ __forceinline__ float dppadd(float x) {
  int s = __builtin_amdgcn_update_dpp(0, __float_as_int(x), CTRL, 0xF, 0xF, true);
  return x + __int_as_float(s);
}
__device__ __forceinline__ float row16_sum(float x) {
  x = dppadd<0xB1>(x);    // quad_perm [1,0,3,2]  : lane ^ 1
  x = dppadd<0x4E>(x);    // quad_perm [2,3,0,1]  : lane ^ 2
  x = dppadd<0x141>(x);   // row_half_mirror
  x = dppadd<0x140>(x);   // row_mirror
  return x;
}

// ---------------------------------------------------------------------------
// Fused prep: blocks [0, nPack) convert x fp32 -> fp16 rows (RNE);
// remaining blocks build the W1 B-fragment table in fp16 (16 frags x 64
// lanes x 8 = 16 KB). Frag f = t*4+s: lane l elem j = W1[s*32+(l>>4)*8+j][t*16+(l&15)].
// ---------------------------------------------------------------------------
__global__ __launch_bounds__(256) void prep(
    const float* __restrict__ x, const float* __restrict__ W1,
    unsigned short* __restrict__ xh, unsigned short* __restrict__ btab,
    int n4, int nPack) {
  int b = blockIdx.x;
  if (b < nPack) {
    int i = b * 256 + threadIdx.x;
    if (i < n4) {
      float4 v = ((const float4*)x)[i];
      ushort4 o;
      o.x = __half_as_ushort(__float2half(v.x));
      o.y = __half_as_ushort(__float2half(v.y));
      o.z = __half_as_ushort(__float2half(v.z));
      o.w = __half_as_ushort(__float2half(v.w));
      ((ushort4*)xh)[i] = o;
    }
  } else {
    int id = (b - nPack) * 256 + threadIdx.x;      // 0..8191
    if (id < 16 * 64 * 8) {
      int j = id & 7;
      int l = (id >> 3) & 63;
      int f = id >> 9;
      int s = f & 3, t = f >> 2;
      int k = s * 32 + (l >> 4) * 8 + j;
      int n = t * 16 + (l & 15);
      btab[id] = __half_as_ushort(__float2half(W1[k * H + n]));
    }
  }
}

// ---------------------------------------------------------------------------
// Compute a PAIR of 16-edge tiles with B-fragment reuse: each of the 16
// B-frags is ds_read ONCE per pair and feeds both tiles' MFMAs. A-frags:
// mu,mv gathered fp16; c,p via packed-fp16 VALU. Bias as MFMA C-input;
// fused layer-2, DPP row-reduce, sigmoid, guarded writes. ebase pre-clamped
// so ebase+31 < nE for reads; store guards keep writes exact.
// R5/R6 LESSON: do NOT edit this function. Hoisting bias vectors or
// packing the epilogue shifts liveness, the allocator retargets the
// 64-VGPR tier, and the gather prefetch gets sunk (39.7 -> 47+ us both
// times). This exact form allocates 84 VGPR and keeps the pipeline.
// ---------------------------------------------------------------------------
__device__ __forceinline__ void compute_pair(
    uint4 mu0U, uint4 mv0U, uint4 mu1U, uint4 mv1U,
    const _Float16* __restrict__ bl,
    const float* __restrict__ b1v, const float* __restrict__ w2v, float bias2,
    int ebase, int q, int m, int nE, float* __restrict__ out) {
  AB mu0, mv0, mu1, mv1, ac0, ap0, ac1, ap1;
  mu0.u = mu0U; mv0.u = mv0U; mu1.u = mu1U; mv1.u = mv1U;
#pragma unroll
  for (int k = 0; k < 4; ++k) {
    ac0.h2[k] = __habs2(__hsub2(mu0.h2[k], mv0.h2[k]));
    ap0.h2[k] = __hmul2(mu0.h2[k], mv0.h2[k]);
    ac1.h2[k] = __habs2(__hsub2(mu1.h2[k], mv1.h2[k]));
    ap1.h2[k] = __hmul2(mu1.h2[k], mv1.h2[k]);
  }

  float part0[4], part1[4];
#pragma unroll
  for (int t = 0; t < 4; ++t) {
    float bv = b1v[t];
    f32x4 acc0 = (f32x4){bv, bv, bv, bv};
    f32x4 acc1 = (f32x4){bv, bv, bv, bv};
    // one ds_read per fragment, two MFMAs (both tiles)
    f16x8 B0 = *(const f16x8*)(bl + (t * 4 + 0) * 512);
    acc0 = __builtin_amdgcn_mfma_f32_16x16x32_f16(mu0.v, B0, acc0, 0, 0, 0);
    acc1 = __builtin_amdgcn_mfma_f32_16x16x32_f16(mu1.v, B0, acc1, 0, 0, 0);
    f16x8 B1 = *(const f16x8*)(bl + (t * 4 + 1) * 512);
    acc0 = __builtin_amdgcn_mfma_f32_16x16x32_f16(mv0.v, B1, acc0, 0, 0, 0);
    acc1 = __builtin_amdgcn_mfma_f32_16x16x32_f16(mv1.v, B1, acc1, 0, 0, 0);
    f16x8 B2 = *(const f16x8*)(bl + (t * 4 + 2) * 512);
    acc0 = __builtin_amdgcn_mfma_f32_16x16x32_f16(ac0.v, B2, acc0, 0, 0, 0);
    acc1 = __builtin_amdgcn_mfma_f32_16x16x32_f16(ac1.v, B2, acc1, 0, 0, 0);
    f16x8 B3 = *(const f16x8*)(bl + (t * 4 + 3) * 512);
    acc0 = __builtin_amdgcn_mfma_f32_16x16x32_f16(ap0.v, B3, acc0, 0, 0, 0);
    acc1 = __builtin_amdgcn_mfma_f32_16x16x32_f16(ap1.v, B3, acc1, 0, 0, 0);
#pragma unroll
    for (int r = 0; r < 4; ++r) {
      float h0 = fmaxf(acc0[r], 0.f);
      float h1 = fmaxf(acc1[r], 0.f);
      part0[r] = (t == 0) ? h0 * w2v[0] : fmaf(h0, w2v[t], part0[r]);
      part1[r] = (t == 0) ? h1 * w2v[0] : fmaf(h1, w2v[t], part1[r]);
    }
  }

#pragma unroll
  for (int r = 0; r < 4; ++r) {
    part0[r] = row16_sum(part0[r]);
    part1[r] = row16_sum(part1[r]);
  }

  if (m < 4) {
    float z0 = (m == 0 ? part0[0] : m == 1 ? part0[1] : m == 2 ? part0[2] : part0[3]) + bias2;
    float z1 = (m == 0 ? part1[0] : m == 1 ? part1[1] : m == 2 ? part1[2] : part1[3]) + bias2;
    int ew0 = ebase + q * 4 + m;
    int ew1 = ebase + 16 + q * 4 + m;
    if (ew0 < nE) out[ew0] = 1.f / (1.f + __expf(-z0));
    if (ew1 < nE) out[ew1] = 1.f / (1.f + __expf(-z1));
  }
}

// ---------------------------------------------------------------------------
// Main: pairs of consecutive 16-edge tiles per wave, grid-stride, hand-
// unrolled x2 (no register-rotation movs). Indices loaded DIRECTLY per lane
// (4 saddr dword loads/pair, each one L1 line, broadcast across q-groups).
// Pair base uniformly clamped to nE-32 (tail recompute idempotent). idx
// prefetched 2 pairs ahead, gathers 1 pair ahead. B table staged into LDS
// with coalesced uint4 copies (zero conflicts). Integer-offset anti-LICM
// opacifier keeps LDS provenance (ds_read_b128).
// PROVEN CONFIGURATION (R2: VGPR 84, edge_mfma 39.7 us, total 109.1):
//  R1 LESSON: (256,8) -> 64-VGPR cap -> spill catastrophe. Keep (256,4).
//  R4 LESSON: 256MiB ws poison fill is UNCONDITIONAL; ws use is free.
//  R5 LESSON: depth-2 prefetch (3 sets) -> allocator de-pipelines to 64 VGPR.
//  R6 LESSON: compute_pair liveness edits -> same cliff. Depth-1, as-is.
// ---------------------------------------------------------------------------
__global__ __launch_bounds__(256, 4) void edge_mfma(
    const unsigned short* __restrict__ xh, const unsigned short* __restrict__ btab,
    const int* __restrict__ ei,
    const float* __restrict__ b1, const float* __restrict__ W2,
    const float* __restrict__ b2, float* __restrict__ out,
    int nE, int nPairs) {
  __shared__ _Float16 lds_b[16 * 64 * 8];   // 16 KB

  // stage B table: 1024 uint4, 256 threads x 4 (coalesced)
  {
    const uint4* src = (const uint4*)btab;
    uint4* dst = (uint4*)lds_b;
#pragma unroll
    for (int i = 0; i < 4; ++i)
      dst[threadIdx.x + i * 256] = src[threadIdx.x + i * 256];
  }
  __syncthreads();

  int lane = threadIdx.x & 63;
  int wid  = (blockIdx.x * 256 + threadIdx.x) >> 6;
  int nW   = (gridDim.x * 256) >> 6;
  int m = lane & 15;        // edge-in-tile (A rows) / hidden-in-tile (C cols)
  int q = lane >> 4;        // quad
  if (wid >= nPairs) return;

  float b1v[4], w2v[4];
#pragma unroll
  for (int t = 0; t < 4; ++t) {
    b1v[t] = b1[t * 16 + m];
    w2v[t] = W2[t * 16 + m];
  }
  float bias2 = b2[0];

  const uint4* xb = (const uint4*)xh;    // node row = 4 uint4; lane reads row*4+q
  const int* eis = ei;                   // src ids
  const int* eid = ei + nE;              // dst ids
  int pLim = nPairs - 1;
  int eCap = nE - 32;                    // launcher guarantees nE >= 32

  // ---- prologue: gathers for pair wid, idx for pair wid+nW ----
  int p = wid;
  int pbC = p * 32; pbC = pbC < eCap ? pbC : eCap;
  uint4 amu0, amu1, amv0, amv1;
  {
    int o0 = pbC + m;
    int ia = eis[o0], ib = eis[o0 + 16], ic = eid[o0], id_ = eid[o0 + 16];
    amu0 = xb[ia * 4 + q]; amu1 = xb[ib * 4 + q];
    amv0 = xb[ic * 4 + q]; amv1 = xb[id_ * 4 + q];
  }
  int ja, jb, jc, jd;
  int pbN;
  {
    int p1 = p + nW; p1 = p1 < pLim ? p1 : pLim;
    pbN = p1 * 32; pbN = pbN < eCap ? pbN : eCap;
    int o1 = pbN + m;
    ja = eis[o1]; jb = eis[o1 + 16]; jc = eid[o1]; jd = eid[o1 + 16];
  }

  uint4 bmu0, bmu1, bmv0, bmv1;
  while (true) {
    // ---- step A: compute A-set, prefetch gathers into B-set ----
    bmu0 = xb[ja * 4 + q]; bmu1 = xb[jb * 4 + q];
    bmv0 = xb[jc * 4 + q]; bmv1 = xb[jd * 4 + q];
    int pb2;
    {
      int p2 = p + 2 * nW; p2 = p2 < pLim ? p2 : pLim;
      pb2 = p2 * 32; pb2 = pb2 < eCap ? pb2 : eCap;
      int o2 = pb2 + m;
      ja = eis[o2]; jb = eis[o2 + 16]; jc = eid[o2]; jd = eid[o2 + 16];
    }
    {
      int bofs = lane * 8;
      asm volatile("" : "+v"(bofs));
      compute_pair(amu0, amv0, amu1, amv1, lds_b + bofs, b1v, w2v, bias2,
                   pbC, q, m, nE, out);
    }
    p += nW; if (p > pLim) return;
    pbC = pbN; pbN = pb2;

    // ---- step B: compute B-set, prefetch gathers into A-set ----
    amu0 = xb[ja * 4 + q]; amu1 = xb[jb * 4 + q];
    amv0 = xb[jc * 4 + q]; amv1 = xb[jd * 4 + q];
    {
      int p2 = p + 2 * nW; p2 = p2 < pLim ? p2 : pLim;
      pb2 = p2 * 32; pb2 = pb2 < eCap ? pb2 : eCap;
      int o2 = pb2 + m;
      ja = eis[o2]; jb = eis[o2 + 16]; jc = eid[o2]; jd = eid[o2 + 16];
    }
    {
      int bofs = lane * 8;
      asm volatile("" : "+v"(bofs));
      compute_pair(bmu0, bmv0, bmu1, bmv1, lds_b + bofs, b1v, w2v, bias2,
                   pbC, q, m, nE, out);
    }
    p += nW; if (p > pLim) return;
    pbC = pbN; pbN = pb2;
  }
}

// ---------------------------------------------------------------------------
// Fallback (ws too small or nE < 32): all-fp32 per edge, no workspace needed.
// ---------------------------------------------------------------------------
__global__ __launch_bounds__(256) void edge_full(
    const float* __restrict__ x, const int* __restrict__ ei,
    const float* __restrict__ W1, const float* __restrict__ b1,
    const float* __restrict__ W2, const float* __restrict__ b2,
    float* __restrict__ out, int nE) {
  int e = blockIdx.x * 256 + threadIdx.x;
  if (e >= nE) return;
  int s = ei[e];
  int d = ei[e + nE];
  const float4* mu4 = (const float4*)(x + (size_t)s * D);
  const float4* mv4 = (const float4*)(x + (size_t)d * D);
  float mu[D], mv[D], c[D], p[D];
#pragma unroll
  for (int qq = 0; qq < D / 4; ++qq) {
    float4 a = mu4[qq];
    float4 b = mv4[qq];
    mu[4*qq+0] = a.x; mv[4*qq+0] = b.x; c[4*qq+0] = fabsf(a.x-b.x); p[4*qq+0] = a.x*b.x;
    mu[4*qq+1] = a.y; mv[4*qq+1] = b.y; c[4*qq+1] = fabsf(a.y-b.y); p[4*qq+1] = a.y*b.y;
    mu[4*qq+2] = a.z; mv[4*qq+2] = b.z; c[4*qq+2] = fabsf(a.z-b.z); p[4*qq+2] = a.z*b.z;
    mu[4*qq+3] = a.w; mv[4*qq+3] = b.w; c[4*qq+3] = fabsf(a.w-b.w); p[4*qq+3] = a.w*b.w;
  }
  float z = b2[0];
  for (int j = 0; j < H; ++j) {
    float a = b1[j];
#pragma unroll
    for (int k = 0; k < D; ++k) {
      a = fmaf(mu[k], W1[k * H + j], a);
      a = fmaf(mv[k], W1[(D + k) * H + j], a);
      a = fmaf(c[k],  W1[(2 * D + k) * H + j], a);
      a = fmaf(p[k],  W1[(3 * D + k) * H + j], a);
    }
    a = fmaxf(a, 0.f);
    z = fmaf(a, W2[j], z);
  }
  float g = 1.f / (1.f + __expf(-z));
  out[e] = fminf(fmaxf(g, 0.f), 1.f);
}

extern "C" void kernel_launch(void* const* d_in, const int* in_sizes, int n_in,
                              void* d_out, int out_size, void* d_ws, size_t ws_size,
                              hipStream_t stream) {
  const float* x  = (const float*)d_in[0];
  const int*   ei = (const int*)d_in[1];
  const float* W1 = (const float*)d_in[2];
  const float* b1 = (const float*)d_in[3];
  const float* W2 = (const float*)d_in[4];
  const float* b2 = (const float*)d_in[5];
  float* out = (float*)d_out;

  int nN = in_sizes[0] / D;      // 100000
  int nE = in_sizes[1] / 2;      // 1600000

  size_t xh_shorts = (size_t)nN * D;                      // 6.4 MB
  size_t need = (xh_shorts + 16 * 64 * 8) * sizeof(unsigned short);
  if (ws_size >= need && nE >= 32) {
    unsigned short* xh   = (unsigned short*)d_ws;
    unsigned short* btab = xh + xh_shorts;
    int n4 = nN * D / 4;
    int nPack = (n4 + 255) / 256;
    int nBt = (16 * 64 * 8 + 255) / 256;
    prep<<<nPack + nBt, 256, 0, stream>>>(x, W1, xh, btab, n4, nPack);
    int nTiles = (nE + 15) / 16;
    int nPairs = (nTiles + 1) / 2;
    // 4 waves/block x 4 pairs/wave: exact balance for nPairs=50000 (3125 blocks)
    int blocks = (nPairs + 15) / 16;
    if (blocks < 1) blocks = 1;
    edge_mfma<<<blocks, 256, 0, stream>>>(xh, btab, ei, b1, W2, b2, out, nE, nPairs);
  } else {
    edge_full<<<(nE + 255) / 256, 256, 0, stream>>>(x, ei, W1, b1, W2, b2, out, nE);
  }
}

// Round 8
// 120.425 us; speedup vs baseline: 1.8867x; 1.0003x over previous
//
#include <hip/hip_runtime.h>
#include <hip/hip_fp16.h>

#define D 32          // MOTIF_DIM
#define H 64          // HIDDEN

typedef __attribute__((ext_vector_type(8))) _Float16 f16x8;
typedef __attribute__((ext_vector_type(4))) float f32x4;

union AB { uint4 u; f16x8 v; __half2 h2[4]; };

// DPP 16-lane row reduction (rows of 16 = our q-groups). All VALU, no DS.
template <int CTRL>
__device__ __forceinline__ float dppadd(float x) {
  int s = __builtin_amdgcn_update_dpp(0, __float_as_int(x), CTRL, 0xF, 0xF, true);
  return x + __int_as_float(s);
}
__device__ __forceinline__ float row16_sum(float x) {
  x = dppadd<0xB1>(x);    // quad_perm [1,0,3,2]  : lane ^ 1
  x = dppadd<0x4E>(x);    // quad_perm [2,3,0,1]  : lane ^ 2
  x = dppadd<0x141>(x);   // row_half_mirror
  x = dppadd<0x140>(x);   // row_mirror
  return x;
}

// ---------------------------------------------------------------------------
// Fused prep: blocks [0, nPack) convert x fp32 -> fp16 rows (RNE);
// remaining blocks build the W1 B-fragment table in fp16 (16 frags x 64
// lanes x 8 = 16 KB). Frag f = t*4+s: lane l elem j = W1[s*32+(l>>4)*8+j][t*16+(l&15)].
// ---------------------------------------------------------------------------
__global__ __launch_bounds__(256) void prep(
    const float* __restrict__ x, const float* __restrict__ W1,
    unsigned short* __restrict__ xh, unsigned short* __restrict__ btab,
    int n4, int nPack) {
  int b = blockIdx.x;
  if (b < nPack) {
    int i = b * 256 + threadIdx.x;
    if (i < n4) {
      float4 v = ((const float4*)x)[i];
      ushort4 o;
      o.x = __half_as_ushort(__float2half(v.x));
      o.y = __half_as_ushort(__float2half(v.y));
      o.z = __half_as_ushort(__float2half(v.z));
      o.w = __half_as_ushort(__float2half(v.w));
      ((ushort4*)xh)[i] = o;
    }
  } else {
    int id = (b - nPack) * 256 + threadIdx.x;      // 0..8191
    if (id < 16 * 64 * 8) {
      int j = id & 7;
      int l = (id >> 3) & 63;
      int f = id >> 9;
      int s = f & 3, t = f >> 2;
      int k = s * 32 + (l >> 4) * 8 + j;
      int n = t * 16 + (l & 15);
      btab[id] = __half_as_ushort(__float2half(W1[k * H + n]));
    }
  }
}

// ---------------------------------------------------------------------------
// Compute a PAIR of 16-edge tiles with B-fragment reuse: each of the 16
// B-frags is ds_read ONCE per pair and feeds both tiles' MFMAs. A-frags:
// mu,mv gathered fp16; c,p via packed-fp16 VALU. Bias as MFMA C-input;
// fused layer-2, DPP row-reduce, sigmoid, guarded writes. ebase pre-clamped
// so ebase+31 < nE always holds for reads; store guards keep writes exact.
// ---------------------------------------------------------------------------
__device__ __forceinline__ void compute_pair(
    uint4 mu0U, uint4 mv0U, uint4 mu1U, uint4 mv1U,
    const _Float16* __restrict__ bl,
    const float* __restrict__ b1v, const float* __restrict__ w2v, float bias2,
    int ebase, int q, int m, int nE, float* __restrict__ out) {
  AB mu0, mv0, mu1, mv1, ac0, ap0, ac1, ap1;
  mu0.u = mu0U; mv0.u = mv0U; mu1.u = mu1U; mv1.u = mv1U;
#pragma unroll
  for (int k = 0; k < 4; ++k) {
    ac0.h2[k] = __habs2(__hsub2(mu0.h2[k], mv0.h2[k]));
    ap0.h2[k] = __hmul2(mu0.h2[k], mv0.h2[k]);
    ac1.h2[k] = __habs2(__hsub2(mu1.h2[k], mv1.h2[k]));
    ap1.h2[k] = __hmul2(mu1.h2[k], mv1.h2[k]);
  }

  float part0[4], part1[4];
#pragma unroll
  for (int t = 0; t < 4; ++t) {
    float bv = b1v[t];
    f32x4 acc0 = (f32x4){bv, bv, bv, bv};
    f32x4 acc1 = (f32x4){bv, bv, bv, bv};
    // one ds_read per fragment, two MFMAs (both tiles)
    f16x8 B0 = *(const f16x8*)(bl + (t * 4 + 0) * 512);
    acc0 = __builtin_amdgcn_mfma_f32_16x16x32_f16(mu0.v, B0, acc0, 0, 0, 0);
    acc1 = __builtin_amdgcn_mfma_f32_16x16x32_f16(mu1.v, B0, acc1, 0, 0, 0);
    f16x8 B1 = *(const f16x8*)(bl + (t * 4 + 1) * 512);
    acc0 = __builtin_amdgcn_mfma_f32_16x16x32_f16(mv0.v, B1, acc0, 0, 0, 0);
    acc1 = __builtin_amdgcn_mfma_f32_16x16x32_f16(mv1.v, B1, acc1, 0, 0, 0);
    f16x8 B2 = *(const f16x8*)(bl + (t * 4 + 2) * 512);
    acc0 = __builtin_amdgcn_mfma_f32_16x16x32_f16(ac0.v, B2, acc0, 0, 0, 0);
    acc1 = __builtin_amdgcn_mfma_f32_16x16x32_f16(ac1.v, B2, acc1, 0, 0, 0);
    f16x8 B3 = *(const f16x8*)(bl + (t * 4 + 3) * 512);
    acc0 = __builtin_amdgcn_mfma_f32_16x16x32_f16(ap0.v, B3, acc0, 0, 0, 0);
    acc1 = __builtin_amdgcn_mfma_f32_16x16x32_f16(ap1.v, B3, acc1, 0, 0, 0);
#pragma unroll
    for (int r = 0; r < 4; ++r) {
      float h0 = fmaxf(acc0[r], 0.f);
      float h1 = fmaxf(acc1[r], 0.f);
      part0[r] = (t == 0) ? h0 * w2v[0] : fmaf(h0, w2v[t], part0[r]);
      part1[r] = (t == 0) ? h1 * w2v[0] : fmaf(h1, w2v[t], part1[r]);
    }
  }

#pragma unroll
  for (int r = 0; r < 4; ++r) {
    part0[r] = row16_sum(part0[r]);
    part1[r] = row16_sum(part1[r]);
  }

  if (m < 4) {
    float z0 = (m == 0 ? part0[0] : m == 1 ? part0[1] : m == 2 ? part0[2] : part0[3]) + bias2;
    float z1 = (m == 0 ? part1[0] : m == 1 ? part1[1] : m == 2 ? part1[2] : part1[3]) + bias2;
    int ew0 = ebase + q * 4 + m;
    int ew1 = ebase + 16 + q * 4 + m;
    if (ew0 < nE) out[ew0] = 1.f / (1.f + __expf(-z0));
    if (ew1 < nE) out[ew1] = 1.f / (1.f + __expf(-z1));
  }
}

// ---------------------------------------------------------------------------
// Main: pairs of consecutive 16-edge tiles per wave, grid-stride, hand-
// unrolled x2 (no register-rotation movs). Indices loaded DIRECTLY per lane
// (4 saddr dword loads/pair, each one L1 line) -- no ds_bpermute chain.
// Pair base uniformly clamped to nE-32 (tail pair recomputes a few edges,
// idempotent). idx prefetched 2 pairs ahead, gathers 1 pair ahead.
// B table staged into LDS with coalesced uint4 copies; anti-LICM opacifier
// on the INTEGER offset only (pointer opacification kills LDS provenance).
// __launch_bounds__(256,4): 128-VGPR cap. R1 LESSON: (256,8) forced a
// 64-VGPR cap -> allocator landed at 32 + scratch spills (FETCH 90->430 MB,
// 3.4x slower). Live state here is ~80 VGPR; do NOT pin tighter.
// R7 LESSON: the "dead" prologue block below is NOT removable -- deleting
// it flips the allocator to the 60-VGPR tier, sinks the gather prefetch,
// and costs +8 us (47.8 vs 39.7). It CSEs away at the machine level but
// anchors liveness/scheduling on the good side of the 64-reg boundary.
// ---------------------------------------------------------------------------
__global__ __launch_bounds__(256, 4) void edge_mfma(
    const unsigned short* __restrict__ xh, const unsigned short* __restrict__ btab,
    const int* __restrict__ ei,
    const float* __restrict__ b1, const float* __restrict__ W2,
    const float* __restrict__ b2, float* __restrict__ out,
    int nE, int nPairs) {
  __shared__ _Float16 lds_b[16 * 64 * 8];   // 16 KB

  // stage B table: 1024 uint4, 256 threads x 4 (coalesced)
  {
    const uint4* src = (const uint4*)btab;
    uint4* dst = (uint4*)lds_b;
#pragma unroll
    for (int i = 0; i < 4; ++i)
      dst[threadIdx.x + i * 256] = src[threadIdx.x + i * 256];
  }
  __syncthreads();

  int lane = threadIdx.x & 63;
  int wid  = (blockIdx.x * 256 + threadIdx.x) >> 6;
  int nW   = (gridDim.x * 256) >> 6;
  int m = lane & 15;        // edge-in-tile (A rows) / hidden-in-tile (C cols)
  int q = lane >> 4;        // quad
  if (wid >= nPairs) return;

  float b1v[4], w2v[4];
#pragma unroll
  for (int t = 0; t < 4; ++t) {
    b1v[t] = b1[t * 16 + m];
    w2v[t] = W2[t * 16 + m];
  }
  float bias2 = b2[0];

  const uint4* xb = (const uint4*)xh;    // node row = 4 uint4; lane reads row*4+q
  const int* eis = ei;                   // src ids
  const int* eid = ei + nE;              // dst ids
  int pLim = nPairs - 1;
  int eCap = nE - 32;                    // launcher guarantees nE >= 32

  // ---- prologue: gathers for pair wid, idx for pair wid+nW ----
  int p = wid;
  int pbC = p * 32; pbC = pbC < eCap ? pbC : eCap;
  {
    int o0 = pbC + m;
    int ia = eis[o0], ib = eis[o0 + 16], ic = eid[o0], id_ = eid[o0 + 16];
    // fallthrough into gathers below via a/b names
    uint4 t0 = xb[ia * 4 + q], t1 = xb[ib * 4 + q];
    uint4 t2 = xb[ic * 4 + q], t3 = xb[id_ * 4 + q];
    // assign to the rotating register set A
    // (SSA: these are the pair-p gathers)
    // store into named regs:
    // amu0,amu1 = src rows tile0/1 ; amv0,amv1 = dst rows tile0/1
    #define AMU0 t0
    // -- use direct variables instead of macros below --
    // (kept simple: re-declare outside this scope)
    asm volatile("" ::);  // no-op
    // move out of scope via globals below
    // NOTE: restructured right after this block.
    (void)t0; (void)t1; (void)t2; (void)t3;
  }
  // Restructured prologue (kept linear for clean SSA):
  uint4 amu0, amu1, amv0, amv1;
  {
    int o0 = pbC + m;
    int ia = eis[o0], ib = eis[o0 + 16], ic = eid[o0], id_ = eid[o0 + 16];
    amu0 = xb[ia * 4 + q]; amu1 = xb[ib * 4 + q];
    amv0 = xb[ic * 4 + q]; amv1 = xb[id_ * 4 + q];
  }
  int ja, jb, jc, jd;
  int pbN;
  {
    int p1 = p + nW; p1 = p1 < pLim ? p1 : pLim;
    pbN = p1 * 32; pbN = pbN < eCap ? pbN : eCap;
    int o1 = pbN + m;
    ja = eis[o1]; jb = eis[o1 + 16]; jc = eid[o1]; jd = eid[o1 + 16];
  }

  uint4 bmu0, bmu1, bmv0, bmv1;
  while (true) {
    // ---- step A: compute A-set, prefetch gathers into B-set ----
    bmu0 = xb[ja * 4 + q]; bmu1 = xb[jb * 4 + q];
    bmv0 = xb[jc * 4 + q]; bmv1 = xb[jd * 4 + q];
    int pb2;
    {
      int p2 = p + 2 * nW; p2 = p2 < pLim ? p2 : pLim;
      pb2 = p2 * 32; pb2 = pb2 < eCap ? pb2 : eCap;
      int o2 = pb2 + m;
      ja = eis[o2]; jb = eis[o2 + 16]; jc = eid[o2]; jd = eid[o2 + 16];
    }
    {
      int bofs = lane * 8;
      asm volatile("" : "+v"(bofs));
      compute_pair(amu0, amv0, amu1, amv1, lds_b + bofs, b1v, w2v, bias2,
                   pbC, q, m, nE, out);
    }
    p += nW; if (p > pLim) return;
    pbC = pbN; pbN = pb2;

    // ---- step B: compute B-set, prefetch gathers into A-set ----
    amu0 = xb[ja * 4 + q]; amu1 = xb[jb * 4 + q];
    amv0 = xb[jc * 4 + q]; amv1 = xb[jd * 4 + q];
    {
      int p2 = p + 2 * nW; p2 = p2 < pLim ? p2 : pLim;
      pb2 = p2 * 32; pb2 = pb2 < eCap ? pb2 : eCap;
      int o2 = pb2 + m;
      ja = eis[o2]; jb = eis[o2 + 16]; jc = eid[o2]; jd = eid[o2 + 16];
    }
    {
      int bofs = lane * 8;
      asm volatile("" : "+v"(bofs));
      compute_pair(bmu0, bmv0, bmu1, bmv1, lds_b + bofs, b1v, w2v, bias2,
                   pbC, q, m, nE, out);
    }
    p += nW; if (p > pLim) return;
    pbC = pbN; pbN = pb2;
  }
}

// ---------------------------------------------------------------------------
// Fallback (ws too small or nE < 32): all-fp32 per edge, no workspace needed.
// ---------------------------------------------------------------------------
__global__ __launch_bounds__(256) void edge_full(
    const float* __restrict__ x, const int* __restrict__ ei,
    const float* __restrict__ W1, const float* __restrict__ b1,
    const float* __restrict__ W2, const float* __restrict__ b2,
    float* __restrict__ out, int nE) {
  int e = blockIdx.x * 256 + threadIdx.x;
  if (e >= nE) return;
  int s = ei[e];
  int d = ei[e + nE];
  const float4* mu4 = (const float4*)(x + (size_t)s * D);
  const float4* mv4 = (const float4*)(x + (size_t)d * D);
  float mu[D], mv[D], c[D], p[D];
#pragma unroll
  for (int qq = 0; qq < D / 4; ++qq) {
    float4 a = mu4[qq];
    float4 b = mv4[qq];
    mu[4*qq+0] = a.x; mv[4*qq+0] = b.x; c[4*qq+0] = fabsf(a.x-b.x); p[4*qq+0] = a.x*b.x;
    mu[4*qq+1] = a.y; mv[4*qq+1] = b.y; c[4*qq+1] = fabsf(a.y-b.y); p[4*qq+1] = a.y*b.y;
    mu[4*qq+2] = a.z; mv[4*qq+2] = b.z; c[4*qq+2] = fabsf(a.z-b.z); p[4*qq+2] = a.z*b.z;
    mu[4*qq+3] = a.w; mv[4*qq+3] = b.w; c[4*qq+3] = fabsf(a.w-b.w); p[4*qq+3] = a.w*b.w;
  }
  float z = b2[0];
  for (int j = 0; j < H; ++j) {
    float a = b1[j];
#pragma unroll
    for (int k = 0; k < D; ++k) {
      a = fmaf(mu[k], W1[k * H + j], a);
      a = fmaf(mv[k], W1[(D + k) * H + j], a);
      a = fmaf(c[k],  W1[(2 * D + k) * H + j], a);
      a = fmaf(p[k],  W1[(3 * D + k) * H + j], a);
    }
    a = fmaxf(a, 0.f);
    z = fmaf(a, W2[j], z);
  }
  float g = 1.f / (1.f + __expf(-z));
  out[e] = fminf(fmaxf(g, 0.f), 1.f);
}

extern "C" void kernel_launch(void* const* d_in, const int* in_sizes, int n_in,
                              void* d_out, int out_size, void* d_ws, size_t ws_size,
                              hipStream_t stream) {
  const float* x  = (const float*)d_in[0];
  const int*   ei = (const int*)d_in[1];
  const float* W1 = (const float*)d_in[2];
  const float* b1 = (const float*)d_in[3];
  const float* W2 = (const float*)d_in[4];
  const float* b2 = (const float*)d_in[5];
  float* out = (float*)d_out;

  int nN = in_sizes[0] / D;      // 100000
  int nE = in_sizes[1] / 2;      // 1600000

  size_t xh_shorts = (size_t)nN * D;                      // 6.4 MB
  size_t need = (xh_shorts + 16 * 64 * 8) * sizeof(unsigned short);
  if (ws_size >= need && nE >= 32) {
    unsigned short* xh   = (unsigned short*)d_ws;
    unsigned short* btab = xh + xh_shorts;
    int n4 = nN * D / 4;
    int nPack = (n4 + 255) / 256;
    int nBt = (16 * 64 * 8 + 255) / 256;
    prep<<<nPack + nBt, 256, 0, stream>>>(x, W1, xh, btab, n4, nPack);
    int nTiles = (nE + 15) / 16;
    int nPairs = (nTiles + 1) / 2;
    // 4 waves/block x 4 pairs/wave: exact balance for nPairs=50000 (3125 blocks)
    int blocks = (nPairs + 15) / 16;
    if (blocks < 1) blocks = 1;
    edge_mfma<<<blocks, 256, 0, stream>>>(xh, btab, ei, b1, W2, b2, out, nE, nPairs);
  } else {
    edge_full<<<(nE + 255) / 256, 256, 0, stream>>>(x, ei, W1, b1, W2, b2, out, nE);
  }
}